// Round 1
// baseline (439.169 us; speedup 1.0000x reference)
//
#include <hip/hip_runtime.h>
#include <math.h>

#define NB   16
#define SLA  1024
#define SLB  1024
#define HH   512

typedef __attribute__((ext_vector_type(4))) float  f32x4;
typedef __attribute__((ext_vector_type(8))) short  s16x8;

__device__ __forceinline__ unsigned short f2bf(float x){
  unsigned u = __float_as_uint(x);
  u += 0x7fffu + ((u >> 16) & 1u);
  return (unsigned short)(u >> 16);
}
__device__ __forceinline__ float bf2f(unsigned short h){
  return __uint_as_float(((unsigned)h) << 16);
}
// fp32 -> (hi bf16, lo bf16) pairs packed into uints
__device__ __forceinline__ void cvt_hilo2(float x, float y, unsigned &hp, unsigned &lp){
  unsigned short hx = f2bf(x);
  unsigned short lx = f2bf(x - bf2f(hx));
  unsigned short hy = f2bf(y);
  unsigned short ly = f2bf(y - bf2f(hy));
  hp = (unsigned)hx | ((unsigned)hy << 16);
  lp = (unsigned)lx | ((unsigned)ly << 16);
}

// ---------------------------------------------------------------------------
// G1: sim[b,i,j] = sum_h A[b,i,h]*B[b,j,h]  (NT GEMM, hi/lo bf16 split MFMA)
// 128x128 tile, 256 threads = 4 waves in 2x2, each wave 64x64 via 4x4 MFMA.
// ---------------------------------------------------------------------------
__global__ __launch_bounds__(256) void sim_gemm_kernel(
    const float* __restrict__ A, const float* __restrict__ Bm,
    float* __restrict__ sim)
{
  // stride 40 ushort (80B): 16B-aligned rows, 2-way-max bank pattern on frag reads
  __shared__ unsigned short sAhi[128][40];
  __shared__ unsigned short sAlo[128][40];
  __shared__ unsigned short sBhi[128][40];
  __shared__ unsigned short sBlo[128][40];

  const int b  = blockIdx.z;
  const int i0 = blockIdx.y * 128;
  const int j0 = blockIdx.x * 128;
  const int t  = threadIdx.x;

  const float* Ab = A  + ((size_t)b * SLA + i0) * HH;
  const float* Bb = Bm + ((size_t)b * SLB + j0) * HH;

  const int r  = t >> 1;           // staging row 0..127
  const int kh = (t & 1) * 16;     // k half 0/16

  const int lane = t & 63;
  const int wr = (t >> 7) & 1;     // wave row
  const int wc = (t >> 6) & 1;     // wave col
  const int q  = lane >> 4;        // quad 0..3
  const int ln = lane & 15;

  f32x4 acc[4][4];
  #pragma unroll
  for (int mt = 0; mt < 4; ++mt)
    #pragma unroll
    for (int nt = 0; nt < 4; ++nt)
      acc[mt][nt] = (f32x4){0.f, 0.f, 0.f, 0.f};

  for (int kb = 0; kb < HH; kb += 32){
    unsigned ah[8], al[8], bh[8], bl[8];
    const float* ga = Ab + (size_t)r * HH + kb + kh;
    const float* gb = Bb + (size_t)r * HH + kb + kh;
    #pragma unroll
    for (int v = 0; v < 4; ++v){
      float4 fa = *(const float4*)(ga + v * 4);
      float4 fb = *(const float4*)(gb + v * 4);
      cvt_hilo2(fa.x, fa.y, ah[v*2],   al[v*2]);
      cvt_hilo2(fa.z, fa.w, ah[v*2+1], al[v*2+1]);
      cvt_hilo2(fb.x, fb.y, bh[v*2],   bl[v*2]);
      cvt_hilo2(fb.z, fb.w, bh[v*2+1], bl[v*2+1]);
    }
    __syncthreads();   // previous iteration's frag reads must finish
    *(uint4*)&sAhi[r][kh]     = make_uint4(ah[0], ah[1], ah[2], ah[3]);
    *(uint4*)&sAhi[r][kh + 8] = make_uint4(ah[4], ah[5], ah[6], ah[7]);
    *(uint4*)&sAlo[r][kh]     = make_uint4(al[0], al[1], al[2], al[3]);
    *(uint4*)&sAlo[r][kh + 8] = make_uint4(al[4], al[5], al[6], al[7]);
    *(uint4*)&sBhi[r][kh]     = make_uint4(bh[0], bh[1], bh[2], bh[3]);
    *(uint4*)&sBhi[r][kh + 8] = make_uint4(bh[4], bh[5], bh[6], bh[7]);
    *(uint4*)&sBlo[r][kh]     = make_uint4(bl[0], bl[1], bl[2], bl[3]);
    *(uint4*)&sBlo[r][kh + 8] = make_uint4(bl[4], bl[5], bl[6], bl[7]);
    __syncthreads();

    // A-frag: m = lane&15, k = quad*8 + j ; B-frag: n = lane&15, k = quad*8 + j
    s16x8 afh[4], afl[4], bfh[4], bfl[4];
    #pragma unroll
    for (int mt = 0; mt < 4; ++mt){
      int ar = wr * 64 + mt * 16 + ln;
      afh[mt] = *(const s16x8*)&sAhi[ar][q * 8];
      afl[mt] = *(const s16x8*)&sAlo[ar][q * 8];
    }
    #pragma unroll
    for (int nt = 0; nt < 4; ++nt){
      int br = wc * 64 + nt * 16 + ln;
      bfh[nt] = *(const s16x8*)&sBhi[br][q * 8];
      bfl[nt] = *(const s16x8*)&sBlo[br][q * 8];
    }
    #pragma unroll
    for (int mt = 0; mt < 4; ++mt)
      #pragma unroll
      for (int nt = 0; nt < 4; ++nt){
        acc[mt][nt] = __builtin_amdgcn_mfma_f32_16x16x32_bf16(afh[mt], bfh[nt], acc[mt][nt], 0, 0, 0);
        acc[mt][nt] = __builtin_amdgcn_mfma_f32_16x16x32_bf16(afh[mt], bfl[nt], acc[mt][nt], 0, 0, 0);
        acc[mt][nt] = __builtin_amdgcn_mfma_f32_16x16x32_bf16(afl[mt], bfh[nt], acc[mt][nt], 0, 0, 0);
      }
  }

  // C/D layout (m89-verified): col = lane&15, row = quad*4 + reg
  float* simb = sim + ((size_t)b * SLA + i0) * SLB + j0;
  #pragma unroll
  for (int mt = 0; mt < 4; ++mt)
    #pragma unroll
    for (int nt = 0; nt < 4; ++nt){
      int col = wc * 64 + nt * 16 + ln;
      #pragma unroll
      for (int rr = 0; rr < 4; ++rr){
        int row = wr * 64 + mt * 16 + q * 4 + rr;
        simb[(size_t)row * SLB + col] = acc[mt][nt][rr];
      }
    }
}

// ---------------------------------------------------------------------------
// Row softmax stats: max & 1/sumexp over hyp-masked j, one wave per (b,i)
// ---------------------------------------------------------------------------
__global__ __launch_bounds__(256) void row_stats_kernel(
    const float* __restrict__ sim, const float* __restrict__ hmask,
    float* __restrict__ rowMax, float* __restrict__ rowInv)
{
  const int wave = threadIdx.x >> 6;
  const int lane = threadIdx.x & 63;
  const int gi = blockIdx.x * 4 + wave;      // b*1024 + i
  const int b  = gi >> 10;
  const float* row = sim + (size_t)gi * SLB;
  const float* mk  = hmask + b * SLB;

  float sv[16], mv[16];
  #pragma unroll
  for (int v = 0; v < 16; ++v){
    int j = lane + v * 64;
    sv[v] = row[j];
    mv[v] = mk[j];
  }
  float mx = -1e30f;
  #pragma unroll
  for (int v = 0; v < 16; ++v)
    if (mv[v] > 0.5f) mx = fmaxf(mx, sv[v]);
  #pragma unroll
  for (int off = 32; off > 0; off >>= 1)
    mx = fmaxf(mx, __shfl_xor(mx, off));
  float sum = 0.f;
  #pragma unroll
  for (int v = 0; v < 16; ++v)
    sum += (mv[v] > 0.5f) ? __expf(sv[v] - mx) : 0.f;
  #pragma unroll
  for (int off = 32; off > 0; off >>= 1)
    sum += __shfl_xor(sum, off);
  if (lane == 0){
    rowMax[gi] = mx;
    rowInv[gi] = 1.f / sum;
  }
}

// ---------------------------------------------------------------------------
// Column softmax stats (over prem-masked i): online partials per i-segment
// ---------------------------------------------------------------------------
__global__ __launch_bounds__(256) void col_stats_partial_kernel(
    const float* __restrict__ sim, const float* __restrict__ pmask,
    float* __restrict__ part)
{
  const int b    = blockIdx.z;
  const int iseg = blockIdx.y;   // 0..7
  const int j    = blockIdx.x * 256 + threadIdx.x;
  const float* sb = sim + (size_t)b * SLA * SLB;
  const float* pm = pmask + b * SLA;

  float m = -1e30f, s = 0.f;
  for (int ii = 0; ii < 128; ++ii){
    int i = iseg * 128 + ii;
    float pmk = pm[i];            // uniform broadcast
    float v = sb[(size_t)i * SLB + j];
    if (pmk > 0.5f){
      float nm = fmaxf(m, v);
      s = s * __expf(m - nm) + __expf(v - nm);
      m = nm;
    }
  }
  size_t o = ((((size_t)b) * 8 + iseg) * SLB + j) * 2;
  part[o] = m; part[o + 1] = s;
}

__global__ __launch_bounds__(256) void col_stats_combine_kernel(
    const float* __restrict__ part,
    float* __restrict__ colMax, float* __restrict__ colInv)
{
  const int g = blockIdx.x * 256 + threadIdx.x;  // b*1024 + j
  const int b = g >> 10, j = g & 1023;
  float M = -1e30f, S = 0.f;
  #pragma unroll
  for (int seg = 0; seg < 8; ++seg){
    size_t o = ((((size_t)b) * 8 + seg) * SLB + j) * 2;
    float m = part[o], s = part[o + 1];
    float nm = fmaxf(M, m);
    S = S * __expf(M - nm) + s * __expf(m - nm);
    M = nm;
  }
  colMax[g] = M;
  colInv[g] = 1.f / S;
}

// ---------------------------------------------------------------------------
// G2/G3: out[b,m,h] = omask[m]*Inv[m]* sum_k kmask[k]*exp(sim(.)-Mx[m]) * V[b,k,h]
// DIR==0: P[m][k] = sim[b, m, k]  (premise side)
// DIR==1: P[m][k] = sim[b, k, m]  (hypothesis side, transposed read)
// ---------------------------------------------------------------------------
template<int DIR>
__global__ __launch_bounds__(256) void av_gemm_kernel(
    const float* __restrict__ sim, const float* __restrict__ V,
    const float* __restrict__ Mx, const float* __restrict__ Inv,
    const float* __restrict__ kmask, const float* __restrict__ omask,
    float* __restrict__ out)
{
  __shared__ unsigned short sP[128][40];   // P[m][k] bf16
  __shared__ unsigned short sV[128][40];   // V^T: sV[n][k] bf16
  __shared__ float sMx[128], sInv[128], sOM[128];
  __shared__ float sKM[1024];

  const int b  = blockIdx.z;
  const int m0 = blockIdx.y * 128;
  const int n0 = blockIdx.x * 128;
  const int t  = threadIdx.x;

  const float* simb = sim + (size_t)b * SLA * SLB;
  const float* Vb   = V + (size_t)b * 1024 * HH;

  if (t < 128){
    sMx[t]  = Mx[b * 1024 + m0 + t];
    sInv[t] = Inv[b * 1024 + m0 + t];
    sOM[t]  = omask[b * 1024 + m0 + t];
  }
  #pragma unroll
  for (int v = 0; v < 4; ++v)
    sKM[t + v * 256] = kmask[b * 1024 + t + v * 256];
  __syncthreads();

  const int lane = t & 63;
  const int wr = (t >> 7) & 1;
  const int wc = (t >> 6) & 1;
  const int q  = lane >> 4;
  const int ln = lane & 15;

  const int kk  = t >> 3;        // 0..31 k-row for transposed staging
  const int a8  = t & 7;         // n = a8 + 8e: spreads banks (2-way, free)
  const int r2  = t >> 1;        // 0..127 m-row (DIR==0 staging)
  const int kh2 = (t & 1) * 16;

  f32x4 acc[4][4];
  #pragma unroll
  for (int mt = 0; mt < 4; ++mt)
    #pragma unroll
    for (int nt = 0; nt < 4; ++nt)
      acc[mt][nt] = (f32x4){0.f, 0.f, 0.f, 0.f};

  for (int k0 = 0; k0 < 1024; k0 += 32){
    // phase 1: global gathers into regs
    float vv[16];
    const float* vrow = Vb + (size_t)(k0 + kk) * HH + n0 + a8;
    #pragma unroll
    for (int e = 0; e < 16; ++e)
      vv[e] = vrow[e * 8];

    unsigned php[8];
    float pv[16];
    if (DIR == 0){
      const float* srow = simb + (size_t)(m0 + r2) * SLB + k0 + kh2;
      float mxr = sMx[r2];
      #pragma unroll
      for (int v = 0; v < 4; ++v){
        float4 f = *(const float4*)(srow + v * 4);
        float p0 = (sKM[k0 + kh2 + v*4 + 0] > 0.5f) ? __expf(f.x - mxr) : 0.f;
        float p1 = (sKM[k0 + kh2 + v*4 + 1] > 0.5f) ? __expf(f.y - mxr) : 0.f;
        float p2 = (sKM[k0 + kh2 + v*4 + 2] > 0.5f) ? __expf(f.z - mxr) : 0.f;
        float p3 = (sKM[k0 + kh2 + v*4 + 3] > 0.5f) ? __expf(f.w - mxr) : 0.f;
        php[v*2]   = (unsigned)f2bf(p0) | ((unsigned)f2bf(p1) << 16);
        php[v*2+1] = (unsigned)f2bf(p2) | ((unsigned)f2bf(p3) << 16);
      }
    } else {
      const float* srow = simb + (size_t)(k0 + kk) * SLB + m0 + a8;
      float km = sKM[k0 + kk];
      bool on = km > 0.5f;
      #pragma unroll
      for (int e = 0; e < 16; ++e){
        float sval = srow[e * 8];
        pv[e] = on ? __expf(sval - sMx[a8 + 8 * e]) : 0.f;
      }
    }

    __syncthreads();
    // phase 2: LDS writes
    #pragma unroll
    for (int e = 0; e < 16; ++e)
      sV[a8 + 8 * e][kk] = f2bf(vv[e]);
    if (DIR == 0){
      *(uint4*)&sP[r2][kh2]     = make_uint4(php[0], php[1], php[2], php[3]);
      *(uint4*)&sP[r2][kh2 + 8] = make_uint4(php[4], php[5], php[6], php[7]);
    } else {
      #pragma unroll
      for (int e = 0; e < 16; ++e)
        sP[a8 + 8 * e][kk] = f2bf(pv[e]);
    }
    __syncthreads();

    // phase 3: MFMA
    s16x8 af[4], bf[4];
    #pragma unroll
    for (int mt = 0; mt < 4; ++mt)
      af[mt] = *(const s16x8*)&sP[wr * 64 + mt * 16 + ln][q * 8];
    #pragma unroll
    for (int nt = 0; nt < 4; ++nt)
      bf[nt] = *(const s16x8*)&sV[wc * 64 + nt * 16 + ln][q * 8];
    #pragma unroll
    for (int mt = 0; mt < 4; ++mt)
      #pragma unroll
      for (int nt = 0; nt < 4; ++nt)
        acc[mt][nt] = __builtin_amdgcn_mfma_f32_16x16x32_bf16(af[mt], bf[nt], acc[mt][nt], 0, 0, 0);
  }

  float* ob = out + (size_t)b * 1024 * HH;
  #pragma unroll
  for (int mt = 0; mt < 4; ++mt)
    #pragma unroll
    for (int nt = 0; nt < 4; ++nt){
      int col = n0 + wc * 64 + nt * 16 + ln;
      #pragma unroll
      for (int rr = 0; rr < 4; ++rr){
        int rowL = wr * 64 + mt * 16 + q * 4 + rr;
        ob[(size_t)(m0 + rowL) * HH + col] = acc[mt][nt][rr] * sInv[rowL] * sOM[rowL];
      }
    }
}

// ---------------------------------------------------------------------------
extern "C" void kernel_launch(void* const* d_in, const int* in_sizes, int n_in,
                              void* d_out, int out_size, void* d_ws, size_t ws_size,
                              hipStream_t stream)
{
  const float* prem  = (const float*)d_in[0];   // [16,1024,512]
  const float* pmask = (const float*)d_in[1];   // [16,1024]
  const float* hyp   = (const float*)d_in[2];   // [16,1024,512]
  const float* hmask = (const float*)d_in[3];   // [16,1024]
  float* out = (float*)d_out;

  // ws layout: sim fp32 (64MB) | rowMax | rowInv | colMax | colInv | colPart
  char* ws = (char*)d_ws;
  float* sim     = (float*)(ws);
  float* rowMax  = (float*)(ws + 67108864);
  float* rowInv  = (float*)(ws + 67108864 + 1 * 65536);
  float* colMax  = (float*)(ws + 67108864 + 2 * 65536);
  float* colInv  = (float*)(ws + 67108864 + 3 * 65536);
  float* colPart = (float*)(ws + 67108864 + 4 * 65536);  // 1 MB
  if (ws_size < (size_t)(67108864 + 4 * 65536 + 1048576)) return;  // need ~65.3 MB

  sim_gemm_kernel<<<dim3(8, 8, NB), 256, 0, stream>>>(prem, hyp, sim);
  row_stats_kernel<<<dim3(4096), 256, 0, stream>>>(sim, hmask, rowMax, rowInv);
  col_stats_partial_kernel<<<dim3(4, 8, NB), 256, 0, stream>>>(sim, pmask, colPart);
  col_stats_combine_kernel<<<dim3(64), 256, 0, stream>>>(colPart, colMax, colInv);
  av_gemm_kernel<0><<<dim3(4, 8, NB), 256, 0, stream>>>(sim, hyp, rowMax, rowInv,
                                                        hmask, pmask, out);
  av_gemm_kernel<1><<<dim3(4, 8, NB), 256, 0, stream>>>(sim, prem, colMax, colInv,
                                                        pmask, hmask,
                                                        out + (size_t)NB * SLA * HH);
}

// Round 2
// 321.340 us; speedup vs baseline: 1.3667x; 1.3667x over previous
//
#include <hip/hip_runtime.h>
#include <math.h>

#define NB   16
#define SLA  1024
#define SLB  1024
#define HH   512

typedef __attribute__((ext_vector_type(4))) float  f32x4;
typedef __attribute__((ext_vector_type(8))) short  s16x8;

__device__ __forceinline__ unsigned short f2bf(float x){
  unsigned u = __float_as_uint(x);
  u += 0x7fffu + ((u >> 16) & 1u);
  return (unsigned short)(u >> 16);
}
__device__ __forceinline__ float bf2f(unsigned short h){
  return __uint_as_float(((unsigned)h) << 16);
}
__device__ __forceinline__ void cvt_hilo2(float x, float y, unsigned &hp, unsigned &lp){
  unsigned short hx = f2bf(x);
  unsigned short lx = f2bf(x - bf2f(hx));
  unsigned short hy = f2bf(y);
  unsigned short ly = f2bf(y - bf2f(hy));
  hp = (unsigned)hx | ((unsigned)hy << 16);
  lp = (unsigned)lx | ((unsigned)ly << 16);
}

// async global->LDS, 16B per lane. LDS dest must be wave-uniform-base + lane*16.
__device__ __forceinline__ void gl2lds16(const void* g, void* l){
  __builtin_amdgcn_global_load_lds(
      (__attribute__((address_space(1))) unsigned int*)(unsigned long long)(size_t)g,
      (__attribute__((address_space(3))) unsigned int*)(unsigned int)(size_t)l,
      16, 0, 0);
}

// ---------------------------------------------------------------------------
// G1: sim[b,i,j] = sum_h A[b,i,h]*B[b,j,h]  (NT GEMM, hi/lo bf16 split MFMA)
// ---------------------------------------------------------------------------
__global__ __launch_bounds__(256) void sim_gemm_kernel(
    const float* __restrict__ A, const float* __restrict__ Bm,
    float* __restrict__ sim)
{
  __shared__ unsigned short sAhi[128][40];
  __shared__ unsigned short sAlo[128][40];
  __shared__ unsigned short sBhi[128][40];
  __shared__ unsigned short sBlo[128][40];

  const int b  = blockIdx.z;
  const int i0 = blockIdx.y * 128;
  const int j0 = blockIdx.x * 128;
  const int t  = threadIdx.x;

  const float* Ab = A  + ((size_t)b * SLA + i0) * HH;
  const float* Bb = Bm + ((size_t)b * SLB + j0) * HH;

  const int r  = t >> 1;
  const int kh = (t & 1) * 16;

  const int lane = t & 63;
  const int wr = (t >> 7) & 1;
  const int wc = (t >> 6) & 1;
  const int q  = lane >> 4;
  const int ln = lane & 15;

  f32x4 acc[4][4];
  #pragma unroll
  for (int mt = 0; mt < 4; ++mt)
    #pragma unroll
    for (int nt = 0; nt < 4; ++nt)
      acc[mt][nt] = (f32x4){0.f, 0.f, 0.f, 0.f};

  for (int kb = 0; kb < HH; kb += 32){
    unsigned ah[8], al[8], bh[8], bl[8];
    const float* ga = Ab + (size_t)r * HH + kb + kh;
    const float* gb = Bb + (size_t)r * HH + kb + kh;
    #pragma unroll
    for (int v = 0; v < 4; ++v){
      float4 fa = *(const float4*)(ga + v * 4);
      float4 fb = *(const float4*)(gb + v * 4);
      cvt_hilo2(fa.x, fa.y, ah[v*2],   al[v*2]);
      cvt_hilo2(fa.z, fa.w, ah[v*2+1], al[v*2+1]);
      cvt_hilo2(fb.x, fb.y, bh[v*2],   bl[v*2]);
      cvt_hilo2(fb.z, fb.w, bh[v*2+1], bl[v*2+1]);
    }
    __syncthreads();
    *(uint4*)&sAhi[r][kh]     = make_uint4(ah[0], ah[1], ah[2], ah[3]);
    *(uint4*)&sAhi[r][kh + 8] = make_uint4(ah[4], ah[5], ah[6], ah[7]);
    *(uint4*)&sAlo[r][kh]     = make_uint4(al[0], al[1], al[2], al[3]);
    *(uint4*)&sAlo[r][kh + 8] = make_uint4(al[4], al[5], al[6], al[7]);
    *(uint4*)&sBhi[r][kh]     = make_uint4(bh[0], bh[1], bh[2], bh[3]);
    *(uint4*)&sBhi[r][kh + 8] = make_uint4(bh[4], bh[5], bh[6], bh[7]);
    *(uint4*)&sBlo[r][kh]     = make_uint4(bl[0], bl[1], bl[2], bl[3]);
    *(uint4*)&sBlo[r][kh + 8] = make_uint4(bl[4], bl[5], bl[6], bl[7]);
    __syncthreads();

    s16x8 afh[4], afl[4], bfh[4], bfl[4];
    #pragma unroll
    for (int mt = 0; mt < 4; ++mt){
      int ar = wr * 64 + mt * 16 + ln;
      afh[mt] = *(const s16x8*)&sAhi[ar][q * 8];
      afl[mt] = *(const s16x8*)&sAlo[ar][q * 8];
    }
    #pragma unroll
    for (int nt = 0; nt < 4; ++nt){
      int br = wc * 64 + nt * 16 + ln;
      bfh[nt] = *(const s16x8*)&sBhi[br][q * 8];
      bfl[nt] = *(const s16x8*)&sBlo[br][q * 8];
    }
    #pragma unroll
    for (int mt = 0; mt < 4; ++mt)
      #pragma unroll
      for (int nt = 0; nt < 4; ++nt){
        acc[mt][nt] = __builtin_amdgcn_mfma_f32_16x16x32_bf16(afh[mt], bfh[nt], acc[mt][nt], 0, 0, 0);
        acc[mt][nt] = __builtin_amdgcn_mfma_f32_16x16x32_bf16(afh[mt], bfl[nt], acc[mt][nt], 0, 0, 0);
        acc[mt][nt] = __builtin_amdgcn_mfma_f32_16x16x32_bf16(afl[mt], bfh[nt], acc[mt][nt], 0, 0, 0);
      }
  }

  float* simb = sim + ((size_t)b * SLA + i0) * SLB + j0;
  #pragma unroll
  for (int mt = 0; mt < 4; ++mt)
    #pragma unroll
    for (int nt = 0; nt < 4; ++nt){
      int col = wc * 64 + nt * 16 + ln;
      #pragma unroll
      for (int rr = 0; rr < 4; ++rr){
        int row = wr * 64 + mt * 16 + q * 4 + rr;
        simb[(size_t)row * SLB + col] = acc[mt][nt][rr];
      }
    }
}

// ---------------------------------------------------------------------------
// Row softmax stats
// ---------------------------------------------------------------------------
__global__ __launch_bounds__(256) void row_stats_kernel(
    const float* __restrict__ sim, const float* __restrict__ hmask,
    float* __restrict__ rowMax, float* __restrict__ rowInv)
{
  const int wave = threadIdx.x >> 6;
  const int lane = threadIdx.x & 63;
  const int gi = blockIdx.x * 4 + wave;
  const int b  = gi >> 10;
  const float* row = sim + (size_t)gi * SLB;
  const float* mk  = hmask + b * SLB;

  float sv[16], mv[16];
  #pragma unroll
  for (int v = 0; v < 16; ++v){
    int j = lane + v * 64;
    sv[v] = row[j];
    mv[v] = mk[j];
  }
  float mx = -1e30f;
  #pragma unroll
  for (int v = 0; v < 16; ++v)
    if (mv[v] > 0.5f) mx = fmaxf(mx, sv[v]);
  #pragma unroll
  for (int off = 32; off > 0; off >>= 1)
    mx = fmaxf(mx, __shfl_xor(mx, off));
  float sum = 0.f;
  #pragma unroll
  for (int v = 0; v < 16; ++v)
    sum += (mv[v] > 0.5f) ? __expf(sv[v] - mx) : 0.f;
  #pragma unroll
  for (int off = 32; off > 0; off >>= 1)
    sum += __shfl_xor(sum, off);
  if (lane == 0){
    rowMax[gi] = mx;
    rowInv[gi] = 1.f / sum;
  }
}

// ---------------------------------------------------------------------------
// Column softmax stats
// ---------------------------------------------------------------------------
__global__ __launch_bounds__(256) void col_stats_partial_kernel(
    const float* __restrict__ sim, const float* __restrict__ pmask,
    float* __restrict__ part)
{
  const int b    = blockIdx.z;
  const int iseg = blockIdx.y;
  const int j    = blockIdx.x * 256 + threadIdx.x;
  const float* sb = sim + (size_t)b * SLA * SLB;
  const float* pm = pmask + b * SLA;

  float m = -1e30f, s = 0.f;
  for (int ii = 0; ii < 128; ++ii){
    int i = iseg * 128 + ii;
    float pmk = pm[i];
    float v = sb[(size_t)i * SLB + j];
    if (pmk > 0.5f){
      float nm = fmaxf(m, v);
      s = s * __expf(m - nm) + __expf(v - nm);
      m = nm;
    }
  }
  size_t o = ((((size_t)b) * 8 + iseg) * SLB + j) * 2;
  part[o] = m; part[o + 1] = s;
}

__global__ __launch_bounds__(256) void col_stats_combine_kernel(
    const float* __restrict__ part,
    float* __restrict__ colMax, float* __restrict__ colInv)
{
  const int g = blockIdx.x * 256 + threadIdx.x;
  float M = -1e30f, S = 0.f;
  const int b = g >> 10, j = g & 1023;
  #pragma unroll
  for (int seg = 0; seg < 8; ++seg){
    size_t o = ((((size_t)b) * 8 + seg) * SLB + j) * 2;
    float m = part[o], s = part[o + 1];
    float nm = fmaxf(M, m);
    S = S * __expf(M - nm) + s * __expf(m - nm);
    M = nm;
  }
  colMax[g] = M;
  colInv[g] = 1.f / S;
}

// ---------------------------------------------------------------------------
// transV: X fp32 [b][1024][512] -> XT bf16 [b][512][1024]  (64x64 LDS tiles)
// blockIdx.z: b + 16*tensor  (tensor 0 = prem, 1 = hyp)
// ---------------------------------------------------------------------------
__global__ __launch_bounds__(256) void trans_v_kernel(
    const float* __restrict__ prem, const float* __restrict__ hyp,
    unsigned short* __restrict__ PremT, unsigned short* __restrict__ HypT)
{
  __shared__ unsigned short tv[64][72];   // [h-local][l-local], 16B-aligned rows

  const int tensor = blockIdx.z >> 4;
  const int b  = blockIdx.z & 15;
  const int l0 = blockIdx.y * 64;
  const int h0 = blockIdx.x * 64;
  const int t  = threadIdx.x;
  const float* X = tensor ? hyp : prem;
  unsigned short* XT = tensor ? HypT : PremT;

  #pragma unroll
  for (int it = 0; it < 4; ++it){
    int r = (t >> 4) + it * 16;        // l-local
    int c = (t & 15) * 4;              // h-local
    float4 x = *(const float4*)(X + ((size_t)b * 1024 + l0 + r) * HH + h0 + c);
    tv[c + 0][r] = f2bf(x.x);
    tv[c + 1][r] = f2bf(x.y);
    tv[c + 2][r] = f2bf(x.z);
    tv[c + 3][r] = f2bf(x.w);
  }
  __syncthreads();
  const int w   = t >> 2;              // h-local 0..63
  const int seg = (t & 3) * 16;        // l-local
  const uint4* src = (const uint4*)&tv[w][seg];
  uint4* dst = (uint4*)(XT + ((size_t)b * HH + h0 + w) * 1024 + l0 + seg);
  dst[0] = src[0];
  dst[1] = src[1];
}

// ---------------------------------------------------------------------------
// buildP: Pprem[b][i][j] = hmask[j]?exp(sim[i][j]-rowMax[i]):0   (bf16, direct)
//         Phyp [b][j][i] = pmask[i]?exp(sim[i][j]-colMax[j]):0   (bf16, transposed)
// ---------------------------------------------------------------------------
__global__ __launch_bounds__(256) void build_p_kernel(
    const float* __restrict__ sim,
    const float* __restrict__ rowMax, const float* __restrict__ colMax,
    const float* __restrict__ pmask,  const float* __restrict__ hmask,
    unsigned short* __restrict__ Pprem, unsigned short* __restrict__ Phyp)
{
  __shared__ unsigned short tp[64][72];  // [j-local][i-local]
  __shared__ float sRM[64], sCM[64], sPM[64], sHM[64];

  const int b  = blockIdx.z;
  const int i0 = blockIdx.y * 64;
  const int j0 = blockIdx.x * 64;
  const int t  = threadIdx.x;

  {
    int which = t >> 6, idx = t & 63;
    if (which == 0) sRM[idx] = rowMax[b * 1024 + i0 + idx];
    if (which == 1) sCM[idx] = colMax[b * 1024 + j0 + idx];
    if (which == 2) sPM[idx] = pmask[b * 1024 + i0 + idx];
    if (which == 3) sHM[idx] = hmask[b * 1024 + j0 + idx];
  }
  __syncthreads();

  const float* sb = sim + (size_t)b * SLA * SLB;
  #pragma unroll
  for (int it = 0; it < 4; ++it){
    int r = (t >> 4) + it * 16;        // i-local
    int c = (t & 15) * 4;              // j-local
    float4 s = *(const float4*)(sb + (size_t)(i0 + r) * SLB + j0 + c);
    float rm = sRM[r];
    unsigned short p0 = f2bf(sHM[c+0] > 0.5f ? __expf(s.x - rm) : 0.f);
    unsigned short p1 = f2bf(sHM[c+1] > 0.5f ? __expf(s.y - rm) : 0.f);
    unsigned short p2 = f2bf(sHM[c+2] > 0.5f ? __expf(s.z - rm) : 0.f);
    unsigned short p3 = f2bf(sHM[c+3] > 0.5f ? __expf(s.w - rm) : 0.f);
    uint2 pk; pk.x = (unsigned)p0 | ((unsigned)p1 << 16);
    pk.y = (unsigned)p2 | ((unsigned)p3 << 16);
    *(uint2*)(Pprem + ((size_t)b * 1024 + i0 + r) * 1024 + j0 + c) = pk;

    bool on = sPM[r] > 0.5f;
    tp[c + 0][r] = f2bf(on ? __expf(s.x - sCM[c+0]) : 0.f);
    tp[c + 1][r] = f2bf(on ? __expf(s.y - sCM[c+1]) : 0.f);
    tp[c + 2][r] = f2bf(on ? __expf(s.z - sCM[c+2]) : 0.f);
    tp[c + 3][r] = f2bf(on ? __expf(s.w - sCM[c+3]) : 0.f);
  }
  __syncthreads();
  const int w   = t >> 2;              // j-local
  const int seg = (t & 3) * 16;        // i-local
  const uint4* src = (const uint4*)&tp[w][seg];
  uint4* dst = (uint4*)(Phyp + ((size_t)b * 1024 + j0 + w) * 1024 + i0 + seg);
  dst[0] = src[0];
  dst[1] = src[1];
}

// ---------------------------------------------------------------------------
// av_bf16: out[m][n] = Inv[m]*om[m] * sum_k A[m][k]*Bt[n][k]
// A: P bf16 [1024][1024], Bt: VT bf16 [512][1024]. 128x128 tile, BK=64,
// global_load_lds staging with XOR chunk swizzle (conflict-free b128 frags).
// blockIdx.z = b + 16*side.
// ---------------------------------------------------------------------------
__global__ __launch_bounds__(256) void av_bf16_kernel(
    const unsigned short* __restrict__ Pprem, const unsigned short* __restrict__ Phyp,
    const unsigned short* __restrict__ HypT,  const unsigned short* __restrict__ PremT,
    const float* __restrict__ rowInv, const float* __restrict__ colInv,
    const float* __restrict__ pmask,  const float* __restrict__ hmask,
    float* __restrict__ out)
{
  __shared__ unsigned short sA[128 * 64];
  __shared__ unsigned short sB[128 * 64];
  __shared__ float sInv[128], sOM[128];

  const int side = blockIdx.z >> 4;
  const int b    = blockIdx.z & 15;
  const int m0   = blockIdx.y * 128;
  const int n0   = blockIdx.x * 128;
  const int t    = threadIdx.x;

  const unsigned short* A  = (side ? Phyp : Pprem) + (size_t)b * 1024 * 1024;
  const unsigned short* Bt = (side ? PremT : HypT) + (size_t)b * 512 * 1024;
  const float* inv = (side ? colInv : rowInv) + b * 1024;
  const float* om  = (side ? hmask : pmask) + b * 1024;
  float* o = out + (size_t)side * NB * SLA * HH + (size_t)b * 1024 * 512;

  if (t < 128){
    sInv[t] = inv[m0 + t];
    sOM[t]  = om[m0 + t];
  }

  const int wv = t >> 6;
  const int L  = t & 63;
  const int lr = L >> 3;               // 0..7 row within 8-row issue
  const int sw = L & 7;                // chunk position within 128B row
  const int gkc = (sw ^ lr) * 8;       // swizzled global k-chunk (elements)

  const int lane = t & 63;
  const int wr = (t >> 7) & 1;
  const int wc = (t >> 6) & 1;
  const int q  = lane >> 4;
  const int ln = lane & 15;
  const int fsw = ln & 7;              // frag-read swizzle key

  f32x4 acc[4][4];
  #pragma unroll
  for (int mt = 0; mt < 4; ++mt)
    #pragma unroll
    for (int nt = 0; nt < 4; ++nt)
      acc[mt][nt] = (f32x4){0.f, 0.f, 0.f, 0.f};

  for (int k0 = 0; k0 < 1024; k0 += 64){
    __syncthreads();   // prior frag reads done before overwrite
    #pragma unroll
    for (int s = 0; s < 4; ++s){
      int row = wv * 32 + s * 8 + lr;
      gl2lds16(A  + (size_t)(m0 + row) * 1024 + k0 + gkc, &sA[row * 64 + sw * 8]);
      gl2lds16(Bt + (size_t)(n0 + row) * 1024 + k0 + gkc, &sB[row * 64 + sw * 8]);
    }
    __syncthreads();   // drains vmcnt -> staged data visible

    #pragma unroll
    for (int h = 0; h < 2; ++h){
      s16x8 af[4], bfr[4];
      #pragma unroll
      for (int mt = 0; mt < 4; ++mt){
        int r = wr * 64 + mt * 16 + ln;
        af[mt] = *(const s16x8*)&sA[r * 64 + (((h << 2) + q) ^ fsw) * 8];
      }
      #pragma unroll
      for (int nt = 0; nt < 4; ++nt){
        int r = wc * 64 + nt * 16 + ln;
        bfr[nt] = *(const s16x8*)&sB[r * 64 + (((h << 2) + q) ^ fsw) * 8];
      }
      #pragma unroll
      for (int mt = 0; mt < 4; ++mt)
        #pragma unroll
        for (int nt = 0; nt < 4; ++nt)
          acc[mt][nt] = __builtin_amdgcn_mfma_f32_16x16x32_bf16(af[mt], bfr[nt], acc[mt][nt], 0, 0, 0);
    }
  }

  #pragma unroll
  for (int mt = 0; mt < 4; ++mt)
    #pragma unroll
    for (int nt = 0; nt < 4; ++nt){
      int col = n0 + wc * 64 + nt * 16 + ln;
      #pragma unroll
      for (int rr = 0; rr < 4; ++rr){
        int rowL = wr * 64 + mt * 16 + q * 4 + rr;
        o[(size_t)(m0 + rowL) * 512 + col] = acc[mt][nt][rr] * sInv[rowL] * sOM[rowL];
      }
    }
}

// ---------------------------------------------------------------------------
// OLD fallback av_gemm (round-1), used only if ws is too small for new path
// ---------------------------------------------------------------------------
template<int DIR>
__global__ __launch_bounds__(256) void av_gemm_kernel(
    const float* __restrict__ sim, const float* __restrict__ V,
    const float* __restrict__ Mx, const float* __restrict__ Inv,
    const float* __restrict__ kmask, const float* __restrict__ omask,
    float* __restrict__ out)
{
  __shared__ unsigned short sP[128][40];
  __shared__ unsigned short sV[128][40];
  __shared__ float sMx[128], sInv[128], sOM[128];
  __shared__ float sKM[1024];

  const int b  = blockIdx.z;
  const int m0 = blockIdx.y * 128;
  const int n0 = blockIdx.x * 128;
  const int t  = threadIdx.x;

  const float* simb = sim + (size_t)b * SLA * SLB;
  const float* Vb   = V + (size_t)b * 1024 * HH;

  if (t < 128){
    sMx[t]  = Mx[b * 1024 + m0 + t];
    sInv[t] = Inv[b * 1024 + m0 + t];
    sOM[t]  = omask[b * 1024 + m0 + t];
  }
  #pragma unroll
  for (int v = 0; v < 4; ++v)
    sKM[t + v * 256] = kmask[b * 1024 + t + v * 256];
  __syncthreads();

  const int lane = t & 63;
  const int wr = (t >> 7) & 1;
  const int wc = (t >> 6) & 1;
  const int q  = lane >> 4;
  const int ln = lane & 15;

  const int kk  = t >> 3;
  const int a8  = t & 7;
  const int r2  = t >> 1;
  const int kh2 = (t & 1) * 16;

  f32x4 acc[4][4];
  #pragma unroll
  for (int mt = 0; mt < 4; ++mt)
    #pragma unroll
    for (int nt = 0; nt < 4; ++nt)
      acc[mt][nt] = (f32x4){0.f, 0.f, 0.f, 0.f};

  for (int k0 = 0; k0 < 1024; k0 += 32){
    float vv[16];
    const float* vrow = Vb + (size_t)(k0 + kk) * HH + n0 + a8;
    #pragma unroll
    for (int e = 0; e < 16; ++e)
      vv[e] = vrow[e * 8];

    unsigned php[8];
    float pv[16];
    if (DIR == 0){
      const float* srow = simb + (size_t)(m0 + r2) * SLB + k0 + kh2;
      float mxr = sMx[r2];
      #pragma unroll
      for (int v = 0; v < 4; ++v){
        float4 f = *(const float4*)(srow + v * 4);
        float p0 = (sKM[k0 + kh2 + v*4 + 0] > 0.5f) ? __expf(f.x - mxr) : 0.f;
        float p1 = (sKM[k0 + kh2 + v*4 + 1] > 0.5f) ? __expf(f.y - mxr) : 0.f;
        float p2 = (sKM[k0 + kh2 + v*4 + 2] > 0.5f) ? __expf(f.z - mxr) : 0.f;
        float p3 = (sKM[k0 + kh2 + v*4 + 3] > 0.5f) ? __expf(f.w - mxr) : 0.f;
        php[v*2]   = (unsigned)f2bf(p0) | ((unsigned)f2bf(p1) << 16);
        php[v*2+1] = (unsigned)f2bf(p2) | ((unsigned)f2bf(p3) << 16);
      }
    } else {
      const float* srow = simb + (size_t)(k0 + kk) * SLB + m0 + a8;
      float km = sKM[k0 + kk];
      bool on = km > 0.5f;
      #pragma unroll
      for (int e = 0; e < 16; ++e){
        float sval = srow[e * 8];
        pv[e] = on ? __expf(sval - sMx[a8 + 8 * e]) : 0.f;
      }
    }

    __syncthreads();
    #pragma unroll
    for (int e = 0; e < 16; ++e)
      sV[a8 + 8 * e][kk] = f2bf(vv[e]);
    if (DIR == 0){
      *(uint4*)&sP[r2][kh2]     = make_uint4(php[0], php[1], php[2], php[3]);
      *(uint4*)&sP[r2][kh2 + 8] = make_uint4(php[4], php[5], php[6], php[7]);
    } else {
      #pragma unroll
      for (int e = 0; e < 16; ++e)
        sP[a8 + 8 * e][kk] = f2bf(pv[e]);
    }
    __syncthreads();

    s16x8 af[4], bf[4];
    #pragma unroll
    for (int mt = 0; mt < 4; ++mt)
      af[mt] = *(const s16x8*)&sP[wr * 64 + mt * 16 + ln][q * 8];
    #pragma unroll
    for (int nt = 0; nt < 4; ++nt)
      bf[nt] = *(const s16x8*)&sV[wc * 64 + nt * 16 + ln][q * 8];
    #pragma unroll
    for (int mt = 0; mt < 4; ++mt)
      #pragma unroll
      for (int nt = 0; nt < 4; ++nt)
        acc[mt][nt] = __builtin_amdgcn_mfma_f32_16x16x32_bf16(af[mt], bf[nt], acc[mt][nt], 0, 0, 0);
  }

  float* ob = out + (size_t)b * 1024 * HH;
  #pragma unroll
  for (int mt = 0; mt < 4; ++mt)
    #pragma unroll
    for (int nt = 0; nt < 4; ++nt){
      int col = n0 + wc * 64 + nt * 16 + ln;
      #pragma unroll
      for (int rr = 0; rr < 4; ++rr){
        int rowL = wr * 64 + mt * 16 + q * 4 + rr;
        ob[(size_t)(m0 + rowL) * HH + col] = acc[mt][nt][rr] * sInv[rowL] * sOM[rowL];
      }
    }
}

// ---------------------------------------------------------------------------
extern "C" void kernel_launch(void* const* d_in, const int* in_sizes, int n_in,
                              void* d_out, int out_size, void* d_ws, size_t ws_size,
                              hipStream_t stream)
{
  const float* prem  = (const float*)d_in[0];
  const float* pmask = (const float*)d_in[1];
  const float* hyp   = (const float*)d_in[2];
  const float* hmask = (const float*)d_in[3];
  float* out = (float*)d_out;

  char* ws = (char*)d_ws;
  float* sim     = (float*)(ws);
  float* rowMax  = (float*)(ws + 67108864);
  float* rowInv  = (float*)(ws + 67108864 + 1 * 65536);
  float* colMax  = (float*)(ws + 67108864 + 2 * 65536);
  float* colInv  = (float*)(ws + 67108864 + 3 * 65536);
  float* colPart = (float*)(ws + 67108864 + 4 * 65536);
  const size_t base2 = 67108864 + 4 * 65536 + 1048576;   // 68419584
  unsigned short* Pprem = (unsigned short*)(ws + base2);
  unsigned short* Phyp  = (unsigned short*)(ws + base2 + 33554432);
  unsigned short* PremT = (unsigned short*)(ws + base2 + 67108864);
  unsigned short* HypT  = (unsigned short*)(ws + base2 + 83886080);
  const size_t need_new = base2 + 100663296;             // ~161.3 MiB

  if (ws_size < base2) return;

  sim_gemm_kernel<<<dim3(8, 8, NB), 256, 0, stream>>>(prem, hyp, sim);
  row_stats_kernel<<<dim3(4096), 256, 0, stream>>>(sim, hmask, rowMax, rowInv);
  col_stats_partial_kernel<<<dim3(4, 8, NB), 256, 0, stream>>>(sim, pmask, colPart);
  col_stats_combine_kernel<<<dim3(64), 256, 0, stream>>>(colPart, colMax, colInv);

  if (ws_size >= need_new){
    trans_v_kernel<<<dim3(8, 16, 32), 256, 0, stream>>>(prem, hyp, PremT, HypT);
    build_p_kernel<<<dim3(16, 16, NB), 256, 0, stream>>>(sim, rowMax, colMax,
                                                         pmask, hmask, Pprem, Phyp);
    av_bf16_kernel<<<dim3(4, 8, 32), 256, 0, stream>>>(Pprem, Phyp, HypT, PremT,
                                                       rowInv, colInv, pmask, hmask, out);
  } else {
    av_gemm_kernel<0><<<dim3(4, 8, NB), 256, 0, stream>>>(sim, hyp, rowMax, rowInv,
                                                          hmask, pmask, out);
    av_gemm_kernel<1><<<dim3(4, 8, NB), 256, 0, stream>>>(sim, prem, colMax, colInv,
                                                          pmask, hmask,
                                                          out + (size_t)NB * SLA * HH);
  }
}

// Round 3
// 298.913 us; speedup vs baseline: 1.4692x; 1.0750x over previous
//
#include <hip/hip_runtime.h>
#include <math.h>

#define NB   16
#define SLA  1024
#define SLB  1024
#define HH   512

typedef __attribute__((ext_vector_type(4))) float  f32x4;
typedef __attribute__((ext_vector_type(8))) short  s16x8;

__device__ __forceinline__ unsigned short f2bf(float x){
  unsigned u = __float_as_uint(x);
  u += 0x7fffu + ((u >> 16) & 1u);
  return (unsigned short)(u >> 16);
}
__device__ __forceinline__ float bf2f(unsigned short h){
  return __uint_as_float(((unsigned)h) << 16);
}

// async global->LDS, 16B per lane. LDS dest must be wave-uniform base + lane*16.
__device__ __forceinline__ void gl2lds16(const void* g, void* l){
  __builtin_amdgcn_global_load_lds(
      (__attribute__((address_space(1))) unsigned int*)(unsigned long long)(size_t)g,
      (__attribute__((address_space(3))) unsigned int*)(unsigned int)(size_t)l,
      16, 0, 0);
}

// ---------------------------------------------------------------------------
// cvt: prem/hyp fp32 [b][1024][512] -> Hi,Lo bf16 [b][1024][512] (k-contig)
//      + HiT bf16 [b][512][1024] (for av V-operand). 64x64 tiles.
// blockIdx.z = b + 16*tensor
// ---------------------------------------------------------------------------
__global__ __launch_bounds__(256) void cvt_kernel(
    const float* __restrict__ prem, const float* __restrict__ hyp,
    unsigned short* __restrict__ premHi, unsigned short* __restrict__ premLo,
    unsigned short* __restrict__ hypHi,  unsigned short* __restrict__ hypLo,
    unsigned short* __restrict__ PremT,  unsigned short* __restrict__ HypT)
{
  __shared__ unsigned short tv[64][72];   // [h-local][l-local] hi for transpose

  const int tensor = blockIdx.z >> 4;
  const int b  = blockIdx.z & 15;
  const int l0 = blockIdx.y * 64;
  const int h0 = blockIdx.x * 64;
  const int t  = threadIdx.x;
  const float* X = tensor ? hyp : prem;
  unsigned short* Hi = tensor ? hypHi : premHi;
  unsigned short* Lo = tensor ? hypLo : premLo;
  unsigned short* XT = tensor ? HypT  : PremT;

  #pragma unroll
  for (int it = 0; it < 4; ++it){
    int r = (t >> 4) + it * 16;        // l-local
    int c = (t & 15) * 4;              // h-local
    size_t go = ((size_t)b * 1024 + l0 + r) * HH + h0 + c;
    float4 x = *(const float4*)(X + go);
    unsigned short h0w = f2bf(x.x), h1w = f2bf(x.y), h2w = f2bf(x.z), h3w = f2bf(x.w);
    unsigned short l0w = f2bf(x.x - bf2f(h0w));
    unsigned short l1w = f2bf(x.y - bf2f(h1w));
    unsigned short l2w = f2bf(x.z - bf2f(h2w));
    unsigned short l3w = f2bf(x.w - bf2f(h3w));
    uint2 hp, lp;
    hp.x = (unsigned)h0w | ((unsigned)h1w << 16);
    hp.y = (unsigned)h2w | ((unsigned)h3w << 16);
    lp.x = (unsigned)l0w | ((unsigned)l1w << 16);
    lp.y = (unsigned)l2w | ((unsigned)l3w << 16);
    *(uint2*)(Hi + go) = hp;
    *(uint2*)(Lo + go) = lp;
    tv[c + 0][r] = h0w;
    tv[c + 1][r] = h1w;
    tv[c + 2][r] = h2w;
    tv[c + 3][r] = h3w;
  }
  __syncthreads();
  const int w   = t >> 2;              // h-local 0..63
  const int seg = (t & 3) * 16;        // l-local
  const uint4* src = (const uint4*)&tv[w][seg];
  uint4* dst = (uint4*)(XT + ((size_t)b * HH + h0 + w) * 1024 + l0 + seg);
  dst[0] = src[0];
  dst[1] = src[1];
}

// ---------------------------------------------------------------------------
// sim_v2: sim[b,i,j] = sum_h A[i][h]*B[j][h], A/B pre-split hi/lo bf16.
// 128x128 tile, BK=32, global_load_lds staging, row-pair XOR swizzle.
// ---------------------------------------------------------------------------
__global__ __launch_bounds__(256) void sim_gemm_v2_kernel(
    const unsigned short* __restrict__ premHi, const unsigned short* __restrict__ premLo,
    const unsigned short* __restrict__ hypHi,  const unsigned short* __restrict__ hypLo,
    float* __restrict__ sim)
{
  __shared__ unsigned short sAh[128 * 32];
  __shared__ unsigned short sAl[128 * 32];
  __shared__ unsigned short sBh[128 * 32];
  __shared__ unsigned short sBl[128 * 32];

  const int b  = blockIdx.z;
  const int i0 = blockIdx.y * 128;
  const int j0 = blockIdx.x * 128;
  const int t  = threadIdx.x;

  const unsigned short* Ah = premHi + ((size_t)b * 1024 + i0) * HH;
  const unsigned short* Al = premLo + ((size_t)b * 1024 + i0) * HH;
  const unsigned short* Bh = hypHi  + ((size_t)b * 1024 + j0) * HH;
  const unsigned short* Bl = hypLo  + ((size_t)b * 1024 + j0) * HH;

  const int wv = t >> 6;
  const int L  = t & 63;
  const int lr = L >> 2;                 // 0..15 row within issue
  const int sw = L & 3;                  // LDS chunk position
  const int gk = (sw ^ ((lr >> 1) & 3)) * 8;  // swizzled global k-offset (elems)

  const int lane = t & 63;
  const int wr = (t >> 7) & 1;
  const int wc = (t >> 6) & 1;
  const int q  = lane >> 4;
  const int ln = lane & 15;
  const int fk = (ln >> 1) & 3;          // frag-read swizzle key

  f32x4 acc[4][4];
  #pragma unroll
  for (int mt = 0; mt < 4; ++mt)
    #pragma unroll
    for (int nt = 0; nt < 4; ++nt)
      acc[mt][nt] = (f32x4){0.f, 0.f, 0.f, 0.f};

  for (int k0 = 0; k0 < HH; k0 += 32){
    __syncthreads();   // prior frag reads done
    #pragma unroll
    for (int s = 0; s < 2; ++s){
      const int r0 = s * 64 + wv * 16;
      const size_t go = (size_t)(r0 + lr) * HH + k0 + gk;
      const int lo = (r0 + lr) * 32 + sw * 8;
      gl2lds16(Ah + go, &sAh[lo]);
      gl2lds16(Al + go, &sAl[lo]);
      gl2lds16(Bh + go, &sBh[lo]);
      gl2lds16(Bl + go, &sBl[lo]);
    }
    __syncthreads();   // vmcnt drained -> staged data visible

    s16x8 afh[4], afl[4], bfh[4], bfl[4];
    #pragma unroll
    for (int mt = 0; mt < 4; ++mt){
      int off = (wr * 64 + mt * 16 + ln) * 32 + ((q ^ fk) * 8);
      afh[mt] = *(const s16x8*)&sAh[off];
      afl[mt] = *(const s16x8*)&sAl[off];
    }
    #pragma unroll
    for (int nt = 0; nt < 4; ++nt){
      int off = (wc * 64 + nt * 16 + ln) * 32 + ((q ^ fk) * 8);
      bfh[nt] = *(const s16x8*)&sBh[off];
      bfl[nt] = *(const s16x8*)&sBl[off];
    }
    #pragma unroll
    for (int mt = 0; mt < 4; ++mt)
      #pragma unroll
      for (int nt = 0; nt < 4; ++nt){
        acc[mt][nt] = __builtin_amdgcn_mfma_f32_16x16x32_bf16(afh[mt], bfh[nt], acc[mt][nt], 0, 0, 0);
        acc[mt][nt] = __builtin_amdgcn_mfma_f32_16x16x32_bf16(afh[mt], bfl[nt], acc[mt][nt], 0, 0, 0);
        acc[mt][nt] = __builtin_amdgcn_mfma_f32_16x16x32_bf16(afl[mt], bfh[nt], acc[mt][nt], 0, 0, 0);
      }
  }

  float* simb = sim + ((size_t)b * SLA + i0) * SLB + j0;
  #pragma unroll
  for (int mt = 0; mt < 4; ++mt)
    #pragma unroll
    for (int nt = 0; nt < 4; ++nt){
      int col = wc * 64 + nt * 16 + ln;
      #pragma unroll
      for (int rr = 0; rr < 4; ++rr){
        int row = wr * 64 + mt * 16 + q * 4 + rr;
        simb[(size_t)row * SLB + col] = acc[mt][nt][rr];
      }
    }
}

// ---------------------------------------------------------------------------
// minmax: exp-free masked maxes. rowMax final; colMax partial per 64-row slab.
// grid (16 slabs, 16 b), wave handles 16 rows.
// ---------------------------------------------------------------------------
__global__ __launch_bounds__(256) void minmax_kernel(
    const float* __restrict__ sim, const float* __restrict__ pmask,
    const float* __restrict__ hmask, float* __restrict__ rowMax,
    float* __restrict__ colMaxPart)
{
  const int islab = blockIdx.x;
  const int b     = blockIdx.y;
  const int wv    = threadIdx.x >> 6;
  const int lane  = threadIdx.x & 63;

  float4 hm[4], cm[4];
  #pragma unroll
  for (int v = 0; v < 4; ++v){
    hm[v] = *(const float4*)(hmask + b * 1024 + lane * 4 + v * 256);
    cm[v] = (float4){-1e30f, -1e30f, -1e30f, -1e30f};
  }

  const int r0 = islab * 64 + wv * 16;
  for (int rr = 0; rr < 16; ++rr){
    const int row = r0 + rr;
    const float* srow = sim + ((size_t)b * 1024 + row) * 1024;
    const float pm = pmask[b * 1024 + row];
    float4 x[4];
    #pragma unroll
    for (int v = 0; v < 4; ++v)
      x[v] = *(const float4*)(srow + lane * 4 + v * 256);

    float rmx = -1e30f;
    #pragma unroll
    for (int v = 0; v < 4; ++v){
      rmx = fmaxf(rmx, hm[v].x > 0.5f ? x[v].x : -1e30f);
      rmx = fmaxf(rmx, hm[v].y > 0.5f ? x[v].y : -1e30f);
      rmx = fmaxf(rmx, hm[v].z > 0.5f ? x[v].z : -1e30f);
      rmx = fmaxf(rmx, hm[v].w > 0.5f ? x[v].w : -1e30f);
    }
    #pragma unroll
    for (int off = 32; off > 0; off >>= 1)
      rmx = fmaxf(rmx, __shfl_xor(rmx, off));
    if (lane == 0) rowMax[b * 1024 + row] = rmx;

    if (pm > 0.5f){
      #pragma unroll
      for (int v = 0; v < 4; ++v){
        cm[v].x = fmaxf(cm[v].x, x[v].x);
        cm[v].y = fmaxf(cm[v].y, x[v].y);
        cm[v].z = fmaxf(cm[v].z, x[v].z);
        cm[v].w = fmaxf(cm[v].w, x[v].w);
      }
    }
  }
  // 4 waves of a block cover different row-groups -> per-(slab,wave) partial?
  // No: all 4 waves share slab; combine via LDS-free trick: each wave writes
  // its own quarter-slab partial (slab id = islab*4 + wv).
  float* dst = colMaxPart + (((size_t)b * 64) + islab * 4 + wv) * 1024;
  #pragma unroll
  for (int v = 0; v < 4; ++v)
    *(float4*)(dst + lane * 4 + v * 256) = cm[v];
}

__global__ __launch_bounds__(256) void colmax_combine_kernel(
    const float* __restrict__ part, float* __restrict__ colMax)
{
  const int g = blockIdx.x * 256 + threadIdx.x;   // 16384
  const int b = g >> 10, j = g & 1023;
  float M = -1e30f;
  #pragma unroll
  for (int seg = 0; seg < 64; ++seg)
    M = fmaxf(M, part[((size_t)b * 64 + seg) * 1024 + j]);
  colMax[g] = M;
}

__global__ __launch_bounds__(256) void zero_kernel(float* __restrict__ a,
                                                   float* __restrict__ b2)
{
  const int g = blockIdx.x * 256 + threadIdx.x;   // 16384 threads
  if (g < 16384){ a[g] = 0.f; b2[g] = 0.f; }
}

__global__ __launch_bounds__(256) void inv_kernel(float* __restrict__ rowS,
                                                  float* __restrict__ colS)
{
  const int g = blockIdx.x * 256 + threadIdx.x;
  if (g < 16384)      rowS[g] = 1.f / rowS[g];
  else                colS[g - 16384] = 1.f / colS[g - 16384];
}

// ---------------------------------------------------------------------------
// build_p_v2: Pprem[b][i][j] = hmask[j]?exp(sim-rowMax[i]):0   (bf16, direct)
//             Phyp [b][j][i] = pmask[i]?exp(sim-colMax[j]):0   (bf16, transposed)
// Also accumulates row sums (of Pprem vals) and col sums (of Phyp vals) into
// rowSumAcc/colSumAcc via one atomicAdd per row/col per tile.
// ---------------------------------------------------------------------------
__global__ __launch_bounds__(256) void build_p_v2_kernel(
    const float* __restrict__ sim,
    const float* __restrict__ rowMax, const float* __restrict__ colMax,
    const float* __restrict__ pmask,  const float* __restrict__ hmask,
    unsigned short* __restrict__ Pprem, unsigned short* __restrict__ Phyp,
    float* __restrict__ rowSumAcc, float* __restrict__ colSumAcc)
{
  __shared__ unsigned short tp[64][72];  // [j-local][i-local]
  __shared__ float sRM[64], sCM[64], sPM[64], sHM[64];

  const int b  = blockIdx.z;
  const int i0 = blockIdx.y * 64;
  const int j0 = blockIdx.x * 64;
  const int t  = threadIdx.x;

  {
    int which = t >> 6, idx = t & 63;
    if (which == 0) sRM[idx] = rowMax[b * 1024 + i0 + idx];
    if (which == 1) sCM[idx] = colMax[b * 1024 + j0 + idx];
    if (which == 2) sPM[idx] = pmask[b * 1024 + i0 + idx];
    if (which == 3) sHM[idx] = hmask[b * 1024 + j0 + idx];
  }
  __syncthreads();

  const float* sb = sim + (size_t)b * SLA * SLB;
  #pragma unroll
  for (int it = 0; it < 4; ++it){
    int r = (t >> 4) + it * 16;        // i-local
    int c = (t & 15) * 4;              // j-local
    float4 s = *(const float4*)(sb + (size_t)(i0 + r) * SLB + j0 + c);
    float rm = sRM[r];
    float p0 = sHM[c+0] > 0.5f ? __expf(s.x - rm) : 0.f;
    float p1 = sHM[c+1] > 0.5f ? __expf(s.y - rm) : 0.f;
    float p2 = sHM[c+2] > 0.5f ? __expf(s.z - rm) : 0.f;
    float p3 = sHM[c+3] > 0.5f ? __expf(s.w - rm) : 0.f;
    uint2 pk;
    pk.x = (unsigned)f2bf(p0) | ((unsigned)f2bf(p1) << 16);
    pk.y = (unsigned)f2bf(p2) | ((unsigned)f2bf(p3) << 16);
    *(uint2*)(Pprem + ((size_t)b * 1024 + i0 + r) * 1024 + j0 + c) = pk;

    // row-sum: reduce p over the 16 threads sharing this row (contig lanes)
    float rs = p0 + p1 + p2 + p3;
    rs += __shfl_xor(rs, 1);
    rs += __shfl_xor(rs, 2);
    rs += __shfl_xor(rs, 4);
    rs += __shfl_xor(rs, 8);
    if ((t & 15) == 0)
      atomicAdd(rowSumAcc + b * 1024 + i0 + r, rs);

    bool on = sPM[r] > 0.5f;
    tp[c + 0][r] = f2bf(on ? __expf(s.x - sCM[c+0]) : 0.f);
    tp[c + 1][r] = f2bf(on ? __expf(s.y - sCM[c+1]) : 0.f);
    tp[c + 2][r] = f2bf(on ? __expf(s.z - sCM[c+2]) : 0.f);
    tp[c + 3][r] = f2bf(on ? __expf(s.w - sCM[c+3]) : 0.f);
  }
  __syncthreads();
  const int w   = t >> 2;              // j-local
  const int seg = (t & 3) * 16;        // i-local
  const uint4* src = (const uint4*)&tp[w][seg];
  uint4 u0 = src[0], u1 = src[1];
  uint4* dst = (uint4*)(Phyp + ((size_t)b * 1024 + j0 + w) * 1024 + i0 + seg);
  dst[0] = u0;
  dst[1] = u1;

  // col-sum from the bf16 transposed values (4 threads per col, contig lanes)
  const unsigned short* us0 = (const unsigned short*)&u0;
  const unsigned short* us1 = (const unsigned short*)&u1;
  float cs = 0.f;
  #pragma unroll
  for (int e = 0; e < 8; ++e) cs += bf2f(us0[e]);
  #pragma unroll
  for (int e = 0; e < 8; ++e) cs += bf2f(us1[e]);
  cs += __shfl_xor(cs, 1);
  cs += __shfl_xor(cs, 2);
  if ((t & 3) == 0)
    atomicAdd(colSumAcc + b * 1024 + j0 + w, cs);
}

// ---------------------------------------------------------------------------
// av_bf16: out[m][n] = Inv[m]*om[m] * sum_k A[m][k]*Bt[n][k]   (unchanged R2)
// ---------------------------------------------------------------------------
__global__ __launch_bounds__(256) void av_bf16_kernel(
    const unsigned short* __restrict__ Pprem, const unsigned short* __restrict__ Phyp,
    const unsigned short* __restrict__ HypT,  const unsigned short* __restrict__ PremT,
    const float* __restrict__ rowInv, const float* __restrict__ colInv,
    const float* __restrict__ pmask,  const float* __restrict__ hmask,
    float* __restrict__ out)
{
  __shared__ unsigned short sA[128 * 64];
  __shared__ unsigned short sB[128 * 64];
  __shared__ float sInv[128], sOM[128];

  const int side = blockIdx.z >> 4;
  const int b    = blockIdx.z & 15;
  const int m0   = blockIdx.y * 128;
  const int n0   = blockIdx.x * 128;
  const int t    = threadIdx.x;

  const unsigned short* A  = (side ? Phyp : Pprem) + (size_t)b * 1024 * 1024;
  const unsigned short* Bt = (side ? PremT : HypT) + (size_t)b * 512 * 1024;
  const float* inv = (side ? colInv : rowInv) + b * 1024;
  const float* om  = (side ? hmask : pmask) + b * 1024;
  float* o = out + (size_t)side * NB * SLA * HH + (size_t)b * 1024 * 512;

  if (t < 128){
    sInv[t] = inv[m0 + t];
    sOM[t]  = om[m0 + t];
  }

  const int wv = t >> 6;
  const int L  = t & 63;
  const int lr = L >> 3;
  const int sw = L & 7;
  const int gkc = (sw ^ lr) * 8;

  const int lane = t & 63;
  const int wr = (t >> 7) & 1;
  const int wc = (t >> 6) & 1;
  const int q  = lane >> 4;
  const int ln = lane & 15;
  const int fsw = ln & 7;

  f32x4 acc[4][4];
  #pragma unroll
  for (int mt = 0; mt < 4; ++mt)
    #pragma unroll
    for (int nt = 0; nt < 4; ++nt)
      acc[mt][nt] = (f32x4){0.f, 0.f, 0.f, 0.f};

  for (int k0 = 0; k0 < 1024; k0 += 64){
    __syncthreads();
    #pragma unroll
    for (int s = 0; s < 4; ++s){
      int row = wv * 32 + s * 8 + lr;
      gl2lds16(A  + (size_t)(m0 + row) * 1024 + k0 + gkc, &sA[row * 64 + sw * 8]);
      gl2lds16(Bt + (size_t)(n0 + row) * 1024 + k0 + gkc, &sB[row * 64 + sw * 8]);
    }
    __syncthreads();

    #pragma unroll
    for (int h = 0; h < 2; ++h){
      s16x8 af[4], bfr[4];
      #pragma unroll
      for (int mt = 0; mt < 4; ++mt){
        int r = wr * 64 + mt * 16 + ln;
        af[mt] = *(const s16x8*)&sA[r * 64 + (((h << 2) + q) ^ fsw) * 8];
      }
      #pragma unroll
      for (int nt = 0; nt < 4; ++nt){
        int r = wc * 64 + nt * 16 + ln;
        bfr[nt] = *(const s16x8*)&sB[r * 64 + (((h << 2) + q) ^ fsw) * 8];
      }
      #pragma unroll
      for (int mt = 0; mt < 4; ++mt)
        #pragma unroll
        for (int nt = 0; nt < 4; ++nt)
          acc[mt][nt] = __builtin_amdgcn_mfma_f32_16x16x32_bf16(af[mt], bfr[nt], acc[mt][nt], 0, 0, 0);
    }
  }

  #pragma unroll
  for (int mt = 0; mt < 4; ++mt)
    #pragma unroll
    for (int nt = 0; nt < 4; ++nt){
      int col = n0 + wc * 64 + nt * 16 + ln;
      #pragma unroll
      for (int rr = 0; rr < 4; ++rr){
        int rowL = wr * 64 + mt * 16 + q * 4 + rr;
        o[(size_t)(m0 + rowL) * 512 + col] = acc[mt][nt][rr] * sInv[rowL] * sOM[rowL];
      }
    }
}

// ---------------------------------------------------------------------------
extern "C" void kernel_launch(void* const* d_in, const int* in_sizes, int n_in,
                              void* d_out, int out_size, void* d_ws, size_t ws_size,
                              hipStream_t stream)
{
  const float* prem  = (const float*)d_in[0];
  const float* pmask = (const float*)d_in[1];
  const float* hyp   = (const float*)d_in[2];
  const float* hmask = (const float*)d_in[3];
  float* out = (float*)d_out;

  char* ws = (char*)d_ws;
  float* sim     = (float*)(ws);
  float* rowMax  = (float*)(ws + 67108864);
  float* rowInv  = (float*)(ws + 67108864 + 1 * 65536);   // sum acc -> inverted
  float* colMax  = (float*)(ws + 67108864 + 2 * 65536);
  float* colInv  = (float*)(ws + 67108864 + 3 * 65536);   // sum acc -> inverted
  float* colMaxPart = (float*)(ws + 67108864 + 4 * 65536); // [16][64][1024] = 4MB? NO:
  // [16][64][1024] floats = 4 MB > 1 MB slot. Use 16*64*1024*4 = 4194304.
  // Slot available: base2-gap is only 1MB. Instead place colMaxPart AFTER the
  // T buffers? T region ends at need; no spare. Solution: colMaxPart aliases
  // the premHi region (base2) — it is written by minmax BEFORE build_p
  // overwrites the region with Pprem, and consumed by colmax_combine which
  // runs before build_p. premHi is dead after sim_gemm_v2. Safe by ordering.
  const size_t base2 = 67108864 + 4 * 65536 + 1048576;   // 68419584
  unsigned short* premHi = (unsigned short*)(ws + base2);
  unsigned short* premLo = (unsigned short*)(ws + base2 + 16777216);
  unsigned short* hypHi  = (unsigned short*)(ws + base2 + 33554432);
  unsigned short* hypLo  = (unsigned short*)(ws + base2 + 50331648);
  unsigned short* PremT  = (unsigned short*)(ws + base2 + 67108864);
  unsigned short* HypT   = (unsigned short*)(ws + base2 + 83886080);
  unsigned short* Pprem  = (unsigned short*)(ws + base2);              // alias premHi/Lo
  unsigned short* Phyp   = (unsigned short*)(ws + base2 + 33554432);   // alias hypHi/Lo
  colMaxPart = (float*)(ws + base2 + 50331648);  // alias hypLo (dead after sim_v2,
                                                 // consumed before build_p writes Phyp)
  const size_t need = base2 + 100663296;         // 169,082,880 (same as R1/R2)
  if (ws_size < need) return;

  cvt_kernel<<<dim3(8, 16, 32), 256, 0, stream>>>(prem, hyp, premHi, premLo,
                                                  hypHi, hypLo, PremT, HypT);
  sim_gemm_v2_kernel<<<dim3(8, 8, NB), 256, 0, stream>>>(premHi, premLo,
                                                         hypHi, hypLo, sim);
  minmax_kernel<<<dim3(16, 16), 256, 0, stream>>>(sim, pmask, hmask,
                                                  rowMax, colMaxPart);
  colmax_combine_kernel<<<dim3(64), 256, 0, stream>>>(colMaxPart, colMax);
  zero_kernel<<<dim3(64), 256, 0, stream>>>(rowInv, colInv);
  build_p_v2_kernel<<<dim3(16, 16, NB), 256, 0, stream>>>(sim, rowMax, colMax,
                                                          pmask, hmask, Pprem, Phyp,
                                                          rowInv, colInv);
  inv_kernel<<<dim3(128), 256, 0, stream>>>(rowInv, colInv);
  av_bf16_kernel<<<dim3(4, 8, 32), 256, 0, stream>>>(Pprem, Phyp, HypT, PremT,
                                                     rowInv, colInv, pmask, hmask, out);
}

// Round 4
// 279.212 us; speedup vs baseline: 1.5729x; 1.0706x over previous
//
#include <hip/hip_runtime.h>
#include <math.h>

#define NB   16
#define SLA  1024
#define SLB  1024
#define HH   512

typedef __attribute__((ext_vector_type(4))) float  f32x4;
typedef __attribute__((ext_vector_type(8))) short  s16x8;
typedef __attribute__((ext_vector_type(4))) int    i32x4;

#define QS    (6.5f / 127.f)
#define QINVS (127.f / 6.5f)

__device__ __forceinline__ unsigned short f2bf(float x){
  unsigned u = __float_as_uint(x);
  u += 0x7fffu + ((u >> 16) & 1u);
  return (unsigned short)(u >> 16);
}
__device__ __forceinline__ float bf2f(unsigned short h){
  return __uint_as_float(((unsigned)h) << 16);
}
// order-preserving float->uint key (monotone); atomicMax-able
__device__ __forceinline__ unsigned fkey(float f){
  unsigned u = __float_as_uint(f);
  return ((int)u < 0) ? ~u : (u | 0x80000000u);
}
__device__ __forceinline__ float funkey(unsigned k){
  return __uint_as_float((k & 0x80000000u) ? (k & 0x7fffffffu) : ~k);
}

// async global->LDS, 16B per lane. LDS dest must be wave-uniform base + lane*16.
__device__ __forceinline__ void gl2lds16(const void* g, void* l){
  __builtin_amdgcn_global_load_lds(
      (__attribute__((address_space(1))) unsigned int*)(unsigned long long)(size_t)g,
      (__attribute__((address_space(3))) unsigned int*)(unsigned int)(size_t)l,
      16, 0, 0);
}

// ---------------------------------------------------------------------------
// init: zero sum accumulators, zero max keys (key 0 < key(any real))
// ---------------------------------------------------------------------------
__global__ __launch_bounds__(256) void init_kernel(
    unsigned* __restrict__ rowMaxU, unsigned* __restrict__ colMaxU,
    float* __restrict__ rowSum, float* __restrict__ colSum)
{
  const int g = blockIdx.x * 256 + threadIdx.x;   // 16384
  rowMaxU[g] = 0u; colMaxU[g] = 0u;
  rowSum[g] = 0.f; colSum[g] = 0.f;
}

// ---------------------------------------------------------------------------
// cvt: X fp32 [b][1024][512] -> i8 digit planes d1,d0 [b][1024][512]
//      + bf16 transposed XT [b][512][1024] (av V-operand). 64x64 tiles.
// blockIdx.z = b + 16*tensor
// ---------------------------------------------------------------------------
__global__ __launch_bounds__(256) void cvt_kernel(
    const float* __restrict__ prem, const float* __restrict__ hyp,
    char* __restrict__ premD1, char* __restrict__ premD0,
    char* __restrict__ hypD1,  char* __restrict__ hypD0,
    unsigned short* __restrict__ PremT, unsigned short* __restrict__ HypT)
{
  __shared__ unsigned short tv[64][72];

  const int tensor = blockIdx.z >> 4;
  const int b  = blockIdx.z & 15;
  const int l0 = blockIdx.y * 64;
  const int h0 = blockIdx.x * 64;
  const int t  = threadIdx.x;
  const float* X = tensor ? hyp : prem;
  char* D1 = tensor ? hypD1 : premD1;
  char* D0 = tensor ? hypD0 : premD0;
  unsigned short* XT = tensor ? HypT : PremT;

  #pragma unroll
  for (int it = 0; it < 4; ++it){
    int r = (t >> 4) + it * 16;        // l-local
    int c = (t & 15) * 4;              // h-local
    size_t go = ((size_t)b * 1024 + l0 + r) * HH + h0 + c;
    float4 x = *(const float4*)(X + go);
    float xv[4] = {x.x, x.y, x.z, x.w};
    char d1v[4], d0v[4];
    #pragma unroll
    for (int e = 0; e < 4; ++e){
      float xs = xv[e] * QINVS;
      float x1 = rintf(xs);
      x1 = fminf(127.f, fmaxf(-127.f, x1));
      float x0 = rintf((xs - x1) * 256.f);
      x0 = fminf(127.f, fmaxf(-128.f, x0));
      d1v[e] = (char)(int)x1;
      d0v[e] = (char)(int)x0;
      tv[c + e][r] = f2bf(xv[e]);
    }
    *(char4*)(D1 + go) = make_char4(d1v[0], d1v[1], d1v[2], d1v[3]);
    *(char4*)(D0 + go) = make_char4(d0v[0], d0v[1], d0v[2], d0v[3]);
  }
  __syncthreads();
  const int w   = t >> 2;
  const int seg = (t & 3) * 16;
  const uint4* src = (const uint4*)&tv[w][seg];
  uint4* dst = (uint4*)(XT + ((size_t)b * HH + h0 + w) * 1024 + l0 + seg);
  dst[0] = src[0];
  dst[1] = src[1];
}

// ---------------------------------------------------------------------------
// sim_v3: sim = s^2*(D1 + Dc/256), D1=sum d1a*d1b, Dc=sum(d1a*d0b + d0a*d1b)
// i8 MFMA 16x16x64, 128x128 tile, BK=64, global_load_lds, XOR chunk swizzle.
// Fused epilogue: masked row/col max -> atomicMax on uint keys.
// ---------------------------------------------------------------------------
__global__ __launch_bounds__(256) void sim_gemm_v3_kernel(
    const char* __restrict__ premD1, const char* __restrict__ premD0,
    const char* __restrict__ hypD1,  const char* __restrict__ hypD0,
    const float* __restrict__ pmask, const float* __restrict__ hmask,
    float* __restrict__ sim,
    unsigned* __restrict__ rowMaxU, unsigned* __restrict__ colMaxU)
{
  __shared__ char sA1[128 * 64];
  __shared__ char sA0[128 * 64];
  __shared__ char sB1[128 * 64];
  __shared__ char sB0[128 * 64];
  __shared__ float sPM[128], sHM[128];

  const int b  = blockIdx.z;
  const int i0 = blockIdx.y * 128;
  const int j0 = blockIdx.x * 128;
  const int t  = threadIdx.x;

  const char* A1 = premD1 + ((size_t)b * 1024 + i0) * HH;
  const char* A0 = premD0 + ((size_t)b * 1024 + i0) * HH;
  const char* B1 = hypD1  + ((size_t)b * 1024 + j0) * HH;
  const char* B0 = hypD0  + ((size_t)b * 1024 + j0) * HH;

  if (t < 128) sPM[t] = pmask[b * 1024 + i0 + t];
  else         sHM[t - 128] = hmask[b * 1024 + j0 + t - 128];

  // staging: row r = s*64 + (t>>2); LDS chunk (t&3) holds global chunk gc
  const int sr  = t >> 2;                       // 0..63
  const int gc  = ((t & 3) ^ ((t >> 3) & 3)) * 16;  // swizzled global chunk (bytes)
  const int lco = (t & 3) * 16;

  const int lane = t & 63;
  const int wr = (t >> 7) & 1;
  const int wc = (t >> 6) & 1;
  const int q  = lane >> 4;
  const int ln = lane & 15;
  const int fo = (q ^ ((ln >> 1) & 3)) * 16;    // frag-read chunk offset (bytes)

  i32x4 acc1[4][4], accc[4][4];
  #pragma unroll
  for (int mt = 0; mt < 4; ++mt)
    #pragma unroll
    for (int nt = 0; nt < 4; ++nt){
      acc1[mt][nt] = (i32x4){0, 0, 0, 0};
      accc[mt][nt] = (i32x4){0, 0, 0, 0};
    }

  for (int k0 = 0; k0 < HH; k0 += 64){
    __syncthreads();   // prior frag reads done; first iter: masks visible
    #pragma unroll
    for (int s = 0; s < 2; ++s){
      const int r = s * 64 + sr;
      const size_t go = (size_t)r * HH + k0 + gc;
      const int lo = r * 64 + lco;
      gl2lds16(A1 + go, &sA1[lo]);
      gl2lds16(A0 + go, &sA0[lo]);
      gl2lds16(B1 + go, &sB1[lo]);
      gl2lds16(B0 + go, &sB0[lo]);
    }
    __syncthreads();   // vmcnt drained -> staged data visible

    i32x4 a1[4], a0[4], b1[4], b0[4];
    #pragma unroll
    for (int mt = 0; mt < 4; ++mt){
      int off = (wr * 64 + mt * 16 + ln) * 64 + fo;
      a1[mt] = *(const i32x4*)&sA1[off];
      a0[mt] = *(const i32x4*)&sA0[off];
    }
    #pragma unroll
    for (int nt = 0; nt < 4; ++nt){
      int off = (wc * 64 + nt * 16 + ln) * 64 + fo;
      b1[nt] = *(const i32x4*)&sB1[off];
      b0[nt] = *(const i32x4*)&sB0[off];
    }
    #pragma unroll
    for (int mt = 0; mt < 4; ++mt)
      #pragma unroll
      for (int nt = 0; nt < 4; ++nt){
        acc1[mt][nt] = __builtin_amdgcn_mfma_i32_16x16x64_i8(a1[mt], b1[nt], acc1[mt][nt], 0, 0, 0);
        accc[mt][nt] = __builtin_amdgcn_mfma_i32_16x16x64_i8(a1[mt], b0[nt], accc[mt][nt], 0, 0, 0);
        accc[mt][nt] = __builtin_amdgcn_mfma_i32_16x16x64_i8(a0[mt], b1[nt], accc[mt][nt], 0, 0, 0);
      }
  }

  // epilogue: sim write + fused masked row/col max
  const float S2 = QS * QS;
  float* simb = sim + ((size_t)b * SLA + i0) * SLB + j0;

  float hmv[4];
  #pragma unroll
  for (int nt = 0; nt < 4; ++nt)
    hmv[nt] = sHM[wc * 64 + nt * 16 + ln];

  float rmx[16];   // [mt*4+rr]
  #pragma unroll
  for (int e = 0; e < 16; ++e) rmx[e] = -1e30f;
  float cmx[4];
  #pragma unroll
  for (int nt = 0; nt < 4; ++nt) cmx[nt] = -1e30f;

  #pragma unroll
  for (int mt = 0; mt < 4; ++mt){
    float pmr[4];
    #pragma unroll
    for (int rr = 0; rr < 4; ++rr)
      pmr[rr] = sPM[wr * 64 + mt * 16 + q * 4 + rr];
    #pragma unroll
    for (int nt = 0; nt < 4; ++nt){
      int col = wc * 64 + nt * 16 + ln;
      #pragma unroll
      for (int rr = 0; rr < 4; ++rr){
        int row = wr * 64 + mt * 16 + q * 4 + rr;
        float f = S2 * ((float)acc1[mt][nt][rr] + (float)accc[mt][nt][rr] * 0.00390625f);
        simb[(size_t)row * SLB + col] = f;
        rmx[mt * 4 + rr] = fmaxf(rmx[mt * 4 + rr], hmv[nt] > 0.5f ? f : -1e30f);
        cmx[nt] = fmaxf(cmx[nt], pmr[rr] > 0.5f ? f : -1e30f);
      }
    }
  }

  // row maxes: reduce across ln (16 lanes of the quad share rows)
  #pragma unroll
  for (int e = 0; e < 16; ++e){
    float v = rmx[e];
    v = fmaxf(v, __shfl_xor(v, 1));
    v = fmaxf(v, __shfl_xor(v, 2));
    v = fmaxf(v, __shfl_xor(v, 4));
    v = fmaxf(v, __shfl_xor(v, 8));
    if (ln == 0){
      int row = wr * 64 + (e >> 2) * 16 + q * 4 + (e & 3);
      atomicMax(rowMaxU + b * 1024 + i0 + row, fkey(v));
    }
  }
  // col maxes: reduce across q (lanes with same ln)
  #pragma unroll
  for (int nt = 0; nt < 4; ++nt){
    float v = cmx[nt];
    v = fmaxf(v, __shfl_xor(v, 16));
    v = fmaxf(v, __shfl_xor(v, 32));
    if (q == 0){
      int col = wc * 64 + nt * 16 + ln;
      atomicMax(colMaxU + b * 1024 + j0 + col, fkey(v));
    }
  }
}

// ---------------------------------------------------------------------------
// inv: x -> 1/x in place (rowSum, colSum -> rowInv, colInv)
// ---------------------------------------------------------------------------
__global__ __launch_bounds__(256) void inv_kernel(float* __restrict__ rowS,
                                                  float* __restrict__ colS)
{
  const int g = blockIdx.x * 256 + threadIdx.x;
  if (g < 16384)      rowS[g] = 1.f / rowS[g];
  else                colS[g - 16384] = 1.f / colS[g - 16384];
}

// ---------------------------------------------------------------------------
// build_p: Pprem[b][i][j] = hmask[j]?exp(sim-rowMax[i]):0   (bf16, direct)
//          Phyp [b][j][i] = pmask[i]?exp(sim-colMax[j]):0   (bf16, transposed)
// accumulates row/col sums via shfl + atomicAdd.
// ---------------------------------------------------------------------------
__global__ __launch_bounds__(256) void build_p_kernel(
    const float* __restrict__ sim,
    const unsigned* __restrict__ rowMaxU, const unsigned* __restrict__ colMaxU,
    const float* __restrict__ pmask,  const float* __restrict__ hmask,
    unsigned short* __restrict__ Pprem, unsigned short* __restrict__ Phyp,
    float* __restrict__ rowSumAcc, float* __restrict__ colSumAcc)
{
  __shared__ unsigned short tp[64][72];
  __shared__ float sRM[64], sCM[64], sPM[64], sHM[64];

  const int b  = blockIdx.z;
  const int i0 = blockIdx.y * 64;
  const int j0 = blockIdx.x * 64;
  const int t  = threadIdx.x;

  {
    int which = t >> 6, idx = t & 63;
    if (which == 0) sRM[idx] = funkey(rowMaxU[b * 1024 + i0 + idx]);
    if (which == 1) sCM[idx] = funkey(colMaxU[b * 1024 + j0 + idx]);
    if (which == 2) sPM[idx] = pmask[b * 1024 + i0 + idx];
    if (which == 3) sHM[idx] = hmask[b * 1024 + j0 + idx];
  }
  __syncthreads();

  const float* sb = sim + (size_t)b * SLA * SLB;
  #pragma unroll
  for (int it = 0; it < 4; ++it){
    int r = (t >> 4) + it * 16;        // i-local
    int c = (t & 15) * 4;              // j-local
    float4 s = *(const float4*)(sb + (size_t)(i0 + r) * SLB + j0 + c);
    float rm = sRM[r];
    float p0 = sHM[c+0] > 0.5f ? __expf(s.x - rm) : 0.f;
    float p1 = sHM[c+1] > 0.5f ? __expf(s.y - rm) : 0.f;
    float p2 = sHM[c+2] > 0.5f ? __expf(s.z - rm) : 0.f;
    float p3 = sHM[c+3] > 0.5f ? __expf(s.w - rm) : 0.f;
    uint2 pk;
    pk.x = (unsigned)f2bf(p0) | ((unsigned)f2bf(p1) << 16);
    pk.y = (unsigned)f2bf(p2) | ((unsigned)f2bf(p3) << 16);
    *(uint2*)(Pprem + ((size_t)b * 1024 + i0 + r) * 1024 + j0 + c) = pk;

    float rs = p0 + p1 + p2 + p3;
    rs += __shfl_xor(rs, 1);
    rs += __shfl_xor(rs, 2);
    rs += __shfl_xor(rs, 4);
    rs += __shfl_xor(rs, 8);
    if ((t & 15) == 0)
      atomicAdd(rowSumAcc + b * 1024 + i0 + r, rs);

    bool on = sPM[r] > 0.5f;
    tp[c + 0][r] = f2bf(on ? __expf(s.x - sCM[c+0]) : 0.f);
    tp[c + 1][r] = f2bf(on ? __expf(s.y - sCM[c+1]) : 0.f);
    tp[c + 2][r] = f2bf(on ? __expf(s.z - sCM[c+2]) : 0.f);
    tp[c + 3][r] = f2bf(on ? __expf(s.w - sCM[c+3]) : 0.f);
  }
  __syncthreads();
  const int w   = t >> 2;
  const int seg = (t & 3) * 16;
  const uint4* src = (const uint4*)&tp[w][seg];
  uint4 u0 = src[0], u1 = src[1];
  uint4* dst = (uint4*)(Phyp + ((size_t)b * 1024 + j0 + w) * 1024 + i0 + seg);
  dst[0] = u0;
  dst[1] = u1;

  const unsigned short* us0 = (const unsigned short*)&u0;
  const unsigned short* us1 = (const unsigned short*)&u1;
  float cs = 0.f;
  #pragma unroll
  for (int e = 0; e < 8; ++e) cs += bf2f(us0[e]);
  #pragma unroll
  for (int e = 0; e < 8; ++e) cs += bf2f(us1[e]);
  cs += __shfl_xor(cs, 1);
  cs += __shfl_xor(cs, 2);
  if ((t & 3) == 0)
    atomicAdd(colSumAcc + b * 1024 + j0 + w, cs);
}

// ---------------------------------------------------------------------------
// av_bf16: out[m][n] = Inv[m]*om[m] * sum_k A[m][k]*Bt[n][k]   (unchanged R3)
// ---------------------------------------------------------------------------
__global__ __launch_bounds__(256) void av_bf16_kernel(
    const unsigned short* __restrict__ Pprem, const unsigned short* __restrict__ Phyp,
    const unsigned short* __restrict__ HypT,  const unsigned short* __restrict__ PremT,
    const float* __restrict__ rowInv, const float* __restrict__ colInv,
    const float* __restrict__ pmask,  const float* __restrict__ hmask,
    float* __restrict__ out)
{
  __shared__ unsigned short sA[128 * 64];
  __shared__ unsigned short sB[128 * 64];
  __shared__ float sInv[128], sOM[128];

  const int side = blockIdx.z >> 4;
  const int b    = blockIdx.z & 15;
  const int m0   = blockIdx.y * 128;
  const int n0   = blockIdx.x * 128;
  const int t    = threadIdx.x;

  const unsigned short* A  = (side ? Phyp : Pprem) + (size_t)b * 1024 * 1024;
  const unsigned short* Bt = (side ? PremT : HypT) + (size_t)b * 512 * 1024;
  const float* inv = (side ? colInv : rowInv) + b * 1024;
  const float* om  = (side ? hmask : pmask) + b * 1024;
  float* o = out + (size_t)side * NB * SLA * HH + (size_t)b * 1024 * 512;

  if (t < 128){
    sInv[t] = inv[m0 + t];
    sOM[t]  = om[m0 + t];
  }

  const int wv = t >> 6;
  const int L  = t & 63;
  const int lr = L >> 3;
  const int sw = L & 7;
  const int gkc = (sw ^ lr) * 8;

  const int lane = t & 63;
  const int wr = (t >> 7) & 1;
  const int wc = (t >> 6) & 1;
  const int q  = lane >> 4;
  const int ln = lane & 15;
  const int fsw = ln & 7;

  f32x4 acc[4][4];
  #pragma unroll
  for (int mt = 0; mt < 4; ++mt)
    #pragma unroll
    for (int nt = 0; nt < 4; ++nt)
      acc[mt][nt] = (f32x4){0.f, 0.f, 0.f, 0.f};

  for (int k0 = 0; k0 < 1024; k0 += 64){
    __syncthreads();
    #pragma unroll
    for (int s = 0; s < 4; ++s){
      int row = wv * 32 + s * 8 + lr;
      gl2lds16(A  + (size_t)(m0 + row) * 1024 + k0 + gkc, &sA[row * 64 + sw * 8]);
      gl2lds16(Bt + (size_t)(n0 + row) * 1024 + k0 + gkc, &sB[row * 64 + sw * 8]);
    }
    __syncthreads();

    #pragma unroll
    for (int h = 0; h < 2; ++h){
      s16x8 af[4], bfr[4];
      #pragma unroll
      for (int mt = 0; mt < 4; ++mt){
        int r = wr * 64 + mt * 16 + ln;
        af[mt] = *(const s16x8*)&sA[r * 64 + (((h << 2) + q) ^ fsw) * 8];
      }
      #pragma unroll
      for (int nt = 0; nt < 4; ++nt){
        int r = wc * 64 + nt * 16 + ln;
        bfr[nt] = *(const s16x8*)&sB[r * 64 + (((h << 2) + q) ^ fsw) * 8];
      }
      #pragma unroll
      for (int mt = 0; mt < 4; ++mt)
        #pragma unroll
        for (int nt = 0; nt < 4; ++nt)
          acc[mt][nt] = __builtin_amdgcn_mfma_f32_16x16x32_bf16(af[mt], bfr[nt], acc[mt][nt], 0, 0, 0);
    }
  }

  #pragma unroll
  for (int mt = 0; mt < 4; ++mt)
    #pragma unroll
    for (int nt = 0; nt < 4; ++nt){
      int col = n0 + wc * 64 + nt * 16 + ln;
      #pragma unroll
      for (int rr = 0; rr < 4; ++rr){
        int rowL = wr * 64 + mt * 16 + q * 4 + rr;
        o[(size_t)(m0 + rowL) * 512 + col] = acc[mt][nt][rr] * sInv[rowL] * sOM[rowL];
      }
    }
}

// ---------------------------------------------------------------------------
extern "C" void kernel_launch(void* const* d_in, const int* in_sizes, int n_in,
                              void* d_out, int out_size, void* d_ws, size_t ws_size,
                              hipStream_t stream)
{
  const float* prem  = (const float*)d_in[0];
  const float* pmask = (const float*)d_in[1];
  const float* hyp   = (const float*)d_in[2];
  const float* hmask = (const float*)d_in[3];
  float* out = (float*)d_out;

  char* ws = (char*)d_ws;
  float*    sim     = (float*)(ws);
  unsigned* rowMaxU = (unsigned*)(ws + 67108864);
  float*    rowInv  = (float*)(ws + 67108864 + 1 * 65536);   // sums -> inverted
  unsigned* colMaxU = (unsigned*)(ws + 67108864 + 2 * 65536);
  float*    colInv  = (float*)(ws + 67108864 + 3 * 65536);   // sums -> inverted
  const size_t base2 = 67108864 + 4 * 65536 + 1048576;   // 68419584 (layout-stable)
  char* premD1 = (char*)(ws + base2);
  char* premD0 = (char*)(ws + base2 + 8388608);
  char* hypD1  = (char*)(ws + base2 + 16777216);
  char* hypD0  = (char*)(ws + base2 + 25165824);
  unsigned short* PremT = (unsigned short*)(ws + base2 + 33554432);
  unsigned short* HypT  = (unsigned short*)(ws + base2 + 50331648);
  // Pprem aliases the digit planes (dead after sim_v3); Phyp in fresh space
  unsigned short* Pprem = (unsigned short*)(ws + base2);
  unsigned short* Phyp  = (unsigned short*)(ws + base2 + 67108864);
  const size_t need = base2 + 100663296;         // 169,082,880 (same as R1-R3)
  if (ws_size < need) return;

  init_kernel<<<dim3(64), 256, 0, stream>>>(rowMaxU, colMaxU, rowInv, colInv);
  cvt_kernel<<<dim3(8, 16, 32), 256, 0, stream>>>(prem, hyp, premD1, premD0,
                                                  hypD1, hypD0, PremT, HypT);
  sim_gemm_v3_kernel<<<dim3(8, 8, NB), 256, 0, stream>>>(premD1, premD0,
                                                         hypD1, hypD0,
                                                         pmask, hmask, sim,
                                                         rowMaxU, colMaxU);
  build_p_kernel<<<dim3(16, 16, NB), 256, 0, stream>>>(sim, rowMaxU, colMaxU,
                                                       pmask, hmask, Pprem, Phyp,
                                                       rowInv, colInv);
  inv_kernel<<<dim3(128), 256, 0, stream>>>(rowInv, colInv);
  av_bf16_kernel<<<dim3(4, 8, 32), 256, 0, stream>>>(Pprem, Phyp, HypT, PremT,
                                                     rowInv, colInv, pmask, hmask, out);
}

// Round 5
// 263.875 us; speedup vs baseline: 1.6643x; 1.0581x over previous
//
#include <hip/hip_runtime.h>
#include <math.h>

#define NB   16
#define SLA  1024
#define SLB  1024
#define HH   512

typedef __attribute__((ext_vector_type(4))) float  f32x4;
typedef __attribute__((ext_vector_type(8))) short  s16x8;
typedef __attribute__((ext_vector_type(4))) int    i32x4;

#define QS    (6.5f / 127.f)
#define QINVS (127.f / 6.5f)

__device__ __forceinline__ unsigned short f2bf(float x){
  unsigned u = __float_as_uint(x);
  u += 0x7fffu + ((u >> 16) & 1u);
  return (unsigned short)(u >> 16);
}
__device__ __forceinline__ float bf2f(unsigned short h){
  return __uint_as_float(((unsigned)h) << 16);
}
// order-preserving float->uint key (monotone); atomicMax-able
__device__ __forceinline__ unsigned fkey(float f){
  unsigned u = __float_as_uint(f);
  return ((int)u < 0) ? ~u : (u | 0x80000000u);
}
__device__ __forceinline__ float funkey(unsigned k){
  return __uint_as_float((k & 0x80000000u) ? (k & 0x7fffffffu) : ~k);
}

// async global->LDS, 16B per lane. LDS dest must be wave-uniform base + lane*16.
__device__ __forceinline__ void gl2lds16(const void* g, void* l){
  __builtin_amdgcn_global_load_lds(
      (__attribute__((address_space(1))) unsigned int*)(unsigned long long)(size_t)g,
      (__attribute__((address_space(3))) unsigned int*)(unsigned int)(size_t)l,
      16, 0, 0);
}

// ---------------------------------------------------------------------------
// init: zero sum accumulators, zero max keys (key 0 < key(any real))
// ---------------------------------------------------------------------------
__global__ __launch_bounds__(256) void init_kernel(
    unsigned* __restrict__ rowMaxU, unsigned* __restrict__ colMaxU,
    float* __restrict__ rowSum, float* __restrict__ colSum)
{
  const int g = blockIdx.x * 256 + threadIdx.x;   // 16384
  rowMaxU[g] = 0u; colMaxU[g] = 0u;
  rowSum[g] = 0.f; colSum[g] = 0.f;
}

// ---------------------------------------------------------------------------
// cvt: X fp32 [b][1024][512] -> i8 digit planes d1,d0 [b][1024][512]
//      + bf16 transposed XT [b][512][1024]. 64x64 tiles. blockIdx.z = b+16*tensor
// ---------------------------------------------------------------------------
__global__ __launch_bounds__(256) void cvt_kernel(
    const float* __restrict__ prem, const float* __restrict__ hyp,
    char* __restrict__ premD1, char* __restrict__ premD0,
    char* __restrict__ hypD1,  char* __restrict__ hypD0,
    unsigned short* __restrict__ PremT, unsigned short* __restrict__ HypT)
{
  __shared__ unsigned short tv[64][72];

  const int tensor = blockIdx.z >> 4;
  const int b  = blockIdx.z & 15;
  const int l0 = blockIdx.y * 64;
  const int h0 = blockIdx.x * 64;
  const int t  = threadIdx.x;
  const float* X = tensor ? hyp : prem;
  char* D1 = tensor ? hypD1 : premD1;
  char* D0 = tensor ? hypD0 : premD0;
  unsigned short* XT = tensor ? HypT : PremT;

  #pragma unroll
  for (int it = 0; it < 4; ++it){
    int r = (t >> 4) + it * 16;        // l-local
    int c = (t & 15) * 4;              // h-local
    size_t go = ((size_t)b * 1024 + l0 + r) * HH + h0 + c;
    float4 x = *(const float4*)(X + go);
    float xv[4] = {x.x, x.y, x.z, x.w};
    char d1v[4], d0v[4];
    #pragma unroll
    for (int e = 0; e < 4; ++e){
      float xs = xv[e] * QINVS;
      float x1 = rintf(xs);
      x1 = fminf(127.f, fmaxf(-127.f, x1));
      float x0 = rintf((xs - x1) * 256.f);
      x0 = fminf(127.f, fmaxf(-128.f, x0));
      d1v[e] = (char)(int)x1;
      d0v[e] = (char)(int)x0;
      tv[c + e][r] = f2bf(xv[e]);
    }
    *(char4*)(D1 + go) = make_char4(d1v[0], d1v[1], d1v[2], d1v[3]);
    *(char4*)(D0 + go) = make_char4(d0v[0], d0v[1], d0v[2], d0v[3]);
  }
  __syncthreads();
  const int w   = t >> 2;
  const int seg = (t & 3) * 16;
  const uint4* src = (const uint4*)&tv[w][seg];
  uint4* dst = (uint4*)(XT + ((size_t)b * HH + h0 + w) * 1024 + l0 + seg);
  dst[0] = src[0];
  dst[1] = src[1];
}

// ---------------------------------------------------------------------------
// sim_v3b: sim = s^2*(D1 + Dc/256). i8 MFMA 16x16x64.
// Block tile 128(M)x64(N), BK=64, 4 waves 2x2, wave tile 64x32.
// acc = 2x(4x2) i32x4 = 64 regs; frags sequenced to cap peak regs.
// Fused epilogue: masked row/col max -> atomicMax on uint keys.
// ---------------------------------------------------------------------------
__global__ __launch_bounds__(256, 3) void sim_gemm_v3b_kernel(
    const char* __restrict__ premD1, const char* __restrict__ premD0,
    const char* __restrict__ hypD1,  const char* __restrict__ hypD0,
    const float* __restrict__ pmask, const float* __restrict__ hmask,
    float* __restrict__ sim,
    unsigned* __restrict__ rowMaxU, unsigned* __restrict__ colMaxU)
{
  __shared__ char sA1[128 * 64];
  __shared__ char sA0[128 * 64];
  __shared__ char sB1[64 * 64];
  __shared__ char sB0[64 * 64];
  __shared__ float sPM[128], sHM[64];

  const int b  = blockIdx.z;
  const int i0 = blockIdx.y * 128;
  const int j0 = blockIdx.x * 64;
  const int t  = threadIdx.x;

  const char* A1 = premD1 + ((size_t)b * 1024 + i0) * HH;
  const char* A0 = premD0 + ((size_t)b * 1024 + i0) * HH;
  const char* B1 = hypD1  + ((size_t)b * 1024 + j0) * HH;
  const char* B0 = hypD0  + ((size_t)b * 1024 + j0) * HH;

  if (t < 128)      sPM[t] = pmask[b * 1024 + i0 + t];
  else if (t < 192) sHM[t - 128] = hmask[b * 1024 + j0 + t - 128];

  // staging: row = (t>>2) [+64], LDS chunk (t&3) holds swizzled global chunk
  const int sr = t >> 2;                            // 0..63
  const int gc = ((t & 3) ^ (sr & 3)) * 16;         // swizzled global chunk (bytes)
  const int lco = (t & 3) * 16;

  const int lane = t & 63;
  const int wr = (t >> 7) & 1;      // M half
  const int wc = (t >> 6) & 1;      // N half
  const int q  = lane >> 4;
  const int ln = lane & 15;
  const int fo = (q ^ (ln & 3)) * 16;   // frag-read chunk offset (bytes)

  i32x4 acc1[4][2], accc[4][2];
  #pragma unroll
  for (int mt = 0; mt < 4; ++mt)
    #pragma unroll
    for (int nt = 0; nt < 2; ++nt){
      acc1[mt][nt] = (i32x4){0, 0, 0, 0};
      accc[mt][nt] = (i32x4){0, 0, 0, 0};
    }

  for (int k0 = 0; k0 < HH; k0 += 64){
    __syncthreads();   // prior frag reads done; first iter: masks visible
    {
      const size_t goA = (size_t)sr * HH + k0 + gc;
      gl2lds16(A1 + goA, &sA1[sr * 64 + lco]);
      gl2lds16(A0 + goA, &sA0[sr * 64 + lco]);
      const size_t goA2 = (size_t)(64 + sr) * HH + k0 + gc;
      gl2lds16(A1 + goA2, &sA1[(64 + sr) * 64 + lco]);
      gl2lds16(A0 + goA2, &sA0[(64 + sr) * 64 + lco]);
      gl2lds16(B1 + goA, &sB1[sr * 64 + lco]);
      gl2lds16(B0 + goA, &sB0[sr * 64 + lco]);
    }
    __syncthreads();   // vmcnt drained -> staged data visible

    i32x4 af[4], bf1[2], bf0[2];
    #pragma unroll
    for (int mt = 0; mt < 4; ++mt)
      af[mt] = *(const i32x4*)&sA1[(wr * 64 + mt * 16 + ln) * 64 + fo];
    #pragma unroll
    for (int nt = 0; nt < 2; ++nt)
      bf1[nt] = *(const i32x4*)&sB1[(wc * 32 + nt * 16 + ln) * 64 + fo];
    #pragma unroll
    for (int mt = 0; mt < 4; ++mt)
      #pragma unroll
      for (int nt = 0; nt < 2; ++nt)
        acc1[mt][nt] = __builtin_amdgcn_mfma_i32_16x16x64_i8(af[mt], bf1[nt], acc1[mt][nt], 0, 0, 0);
    #pragma unroll
    for (int nt = 0; nt < 2; ++nt)
      bf0[nt] = *(const i32x4*)&sB0[(wc * 32 + nt * 16 + ln) * 64 + fo];
    #pragma unroll
    for (int mt = 0; mt < 4; ++mt)
      #pragma unroll
      for (int nt = 0; nt < 2; ++nt)
        accc[mt][nt] = __builtin_amdgcn_mfma_i32_16x16x64_i8(af[mt], bf0[nt], accc[mt][nt], 0, 0, 0);
    #pragma unroll
    for (int mt = 0; mt < 4; ++mt)
      af[mt] = *(const i32x4*)&sA0[(wr * 64 + mt * 16 + ln) * 64 + fo];   // a0 reuses af
    #pragma unroll
    for (int mt = 0; mt < 4; ++mt)
      #pragma unroll
      for (int nt = 0; nt < 2; ++nt)
        accc[mt][nt] = __builtin_amdgcn_mfma_i32_16x16x64_i8(af[mt], bf1[nt], accc[mt][nt], 0, 0, 0);
  }

  // epilogue: sim write + fused masked row/col max
  const float S2 = QS * QS;
  float* simb = sim + ((size_t)b * SLA + i0) * SLB + j0;

  float hmv[2];
  #pragma unroll
  for (int nt = 0; nt < 2; ++nt)
    hmv[nt] = sHM[wc * 32 + nt * 16 + ln];

  float rmx[16];   // [mt*4+rr]
  #pragma unroll
  for (int e = 0; e < 16; ++e) rmx[e] = -1e30f;
  float cmx[2];
  cmx[0] = -1e30f; cmx[1] = -1e30f;

  #pragma unroll
  for (int mt = 0; mt < 4; ++mt){
    float pmr[4];
    #pragma unroll
    for (int rr = 0; rr < 4; ++rr)
      pmr[rr] = sPM[wr * 64 + mt * 16 + q * 4 + rr];
    #pragma unroll
    for (int nt = 0; nt < 2; ++nt){
      int col = wc * 32 + nt * 16 + ln;
      #pragma unroll
      for (int rr = 0; rr < 4; ++rr){
        int row = wr * 64 + mt * 16 + q * 4 + rr;
        float f = S2 * ((float)acc1[mt][nt][rr] + (float)accc[mt][nt][rr] * 0.00390625f);
        simb[(size_t)row * SLB + col] = f;
        rmx[mt * 4 + rr] = fmaxf(rmx[mt * 4 + rr], hmv[nt] > 0.5f ? f : -1e30f);
        cmx[nt] = fmaxf(cmx[nt], pmr[rr] > 0.5f ? f : -1e30f);
      }
    }
  }

  // row maxes: reduce across ln within each q-group
  #pragma unroll
  for (int e = 0; e < 16; ++e){
    float v = rmx[e];
    v = fmaxf(v, __shfl_xor(v, 1));
    v = fmaxf(v, __shfl_xor(v, 2));
    v = fmaxf(v, __shfl_xor(v, 4));
    v = fmaxf(v, __shfl_xor(v, 8));
    if (ln == 0){
      int row = wr * 64 + (e >> 2) * 16 + q * 4 + (e & 3);
      atomicMax(rowMaxU + b * 1024 + i0 + row, fkey(v));
    }
  }
  // col maxes: reduce across q
  #pragma unroll
  for (int nt = 0; nt < 2; ++nt){
    float v = cmx[nt];
    v = fmaxf(v, __shfl_xor(v, 16));
    v = fmaxf(v, __shfl_xor(v, 32));
    if (q == 0){
      int col = wc * 32 + nt * 16 + ln;
      atomicMax(colMaxU + b * 1024 + j0 + col, fkey(v));
    }
  }
}

// ---------------------------------------------------------------------------
// inv: x -> 1/x in place
// ---------------------------------------------------------------------------
__global__ __launch_bounds__(256) void inv_kernel(float* __restrict__ rowS,
                                                  float* __restrict__ colS)
{
  const int g = blockIdx.x * 256 + threadIdx.x;
  if (g < 16384)      rowS[g] = 1.f / rowS[g];
  else                colS[g - 16384] = 1.f / colS[g - 16384];
}

// ---------------------------------------------------------------------------
// build_p: Pprem direct, Phyp transposed (bf16) + row/col sums via atomics
// ---------------------------------------------------------------------------
__global__ __launch_bounds__(256) void build_p_kernel(
    const float* __restrict__ sim,
    const unsigned* __restrict__ rowMaxU, const unsigned* __restrict__ colMaxU,
    const float* __restrict__ pmask,  const float* __restrict__ hmask,
    unsigned short* __restrict__ Pprem, unsigned short* __restrict__ Phyp,
    float* __restrict__ rowSumAcc, float* __restrict__ colSumAcc)
{
  __shared__ unsigned short tp[64][72];
  __shared__ float sRM[64], sCM[64], sPM[64], sHM[64];

  const int b  = blockIdx.z;
  const int i0 = blockIdx.y * 64;
  const int j0 = blockIdx.x * 64;
  const int t  = threadIdx.x;

  {
    int which = t >> 6, idx = t & 63;
    if (which == 0) sRM[idx] = funkey(rowMaxU[b * 1024 + i0 + idx]);
    if (which == 1) sCM[idx] = funkey(colMaxU[b * 1024 + j0 + idx]);
    if (which == 2) sPM[idx] = pmask[b * 1024 + i0 + idx];
    if (which == 3) sHM[idx] = hmask[b * 1024 + j0 + idx];
  }
  __syncthreads();

  const float* sb = sim + (size_t)b * SLA * SLB;
  #pragma unroll
  for (int it = 0; it < 4; ++it){
    int r = (t >> 4) + it * 16;        // i-local
    int c = (t & 15) * 4;              // j-local
    float4 s = *(const float4*)(sb + (size_t)(i0 + r) * SLB + j0 + c);
    float rm = sRM[r];
    float p0 = sHM[c+0] > 0.5f ? __expf(s.x - rm) : 0.f;
    float p1 = sHM[c+1] > 0.5f ? __expf(s.y - rm) : 0.f;
    float p2 = sHM[c+2] > 0.5f ? __expf(s.z - rm) : 0.f;
    float p3 = sHM[c+3] > 0.5f ? __expf(s.w - rm) : 0.f;
    uint2 pk;
    pk.x = (unsigned)f2bf(p0) | ((unsigned)f2bf(p1) << 16);
    pk.y = (unsigned)f2bf(p2) | ((unsigned)f2bf(p3) << 16);
    *(uint2*)(Pprem + ((size_t)b * 1024 + i0 + r) * 1024 + j0 + c) = pk;

    float rs = p0 + p1 + p2 + p3;
    rs += __shfl_xor(rs, 1);
    rs += __shfl_xor(rs, 2);
    rs += __shfl_xor(rs, 4);
    rs += __shfl_xor(rs, 8);
    if ((t & 15) == 0)
      atomicAdd(rowSumAcc + b * 1024 + i0 + r, rs);

    bool on = sPM[r] > 0.5f;
    tp[c + 0][r] = f2bf(on ? __expf(s.x - sCM[c+0]) : 0.f);
    tp[c + 1][r] = f2bf(on ? __expf(s.y - sCM[c+1]) : 0.f);
    tp[c + 2][r] = f2bf(on ? __expf(s.z - sCM[c+2]) : 0.f);
    tp[c + 3][r] = f2bf(on ? __expf(s.w - sCM[c+3]) : 0.f);
  }
  __syncthreads();
  const int w   = t >> 2;
  const int seg = (t & 3) * 16;
  const uint4* src = (const uint4*)&tp[w][seg];
  uint4 u0 = src[0], u1 = src[1];
  uint4* dst = (uint4*)(Phyp + ((size_t)b * 1024 + j0 + w) * 1024 + i0 + seg);
  dst[0] = u0;
  dst[1] = u1;

  const unsigned short* us0 = (const unsigned short*)&u0;
  const unsigned short* us1 = (const unsigned short*)&u1;
  float cs = 0.f;
  #pragma unroll
  for (int e = 0; e < 8; ++e) cs += bf2f(us0[e]);
  #pragma unroll
  for (int e = 0; e < 8; ++e) cs += bf2f(us1[e]);
  cs += __shfl_xor(cs, 1);
  cs += __shfl_xor(cs, 2);
  if ((t & 3) == 0)
    atomicAdd(colSumAcc + b * 1024 + j0 + w, cs);
}

// ---------------------------------------------------------------------------
// av_bf16: out[m][n] = Inv[m]*om[m] * sum_k A[m][k]*Bt[n][k]   (unchanged)
// ---------------------------------------------------------------------------
__global__ __launch_bounds__(256) void av_bf16_kernel(
    const unsigned short* __restrict__ Pprem, const unsigned short* __restrict__ Phyp,
    const unsigned short* __restrict__ HypT,  const unsigned short* __restrict__ PremT,
    const float* __restrict__ rowInv, const float* __restrict__ colInv,
    const float* __restrict__ pmask,  const float* __restrict__ hmask,
    float* __restrict__ out)
{
  __shared__ unsigned short sA[128 * 64];
  __shared__ unsigned short sB[128 * 64];
  __shared__ float sInv[128], sOM[128];

  const int side = blockIdx.z >> 4;
  const int b    = blockIdx.z & 15;
  const int m0   = blockIdx.y * 128;
  const int n0   = blockIdx.x * 128;
  const int t    = threadIdx.x;

  const unsigned short* A  = (side ? Phyp : Pprem) + (size_t)b * 1024 * 1024;
  const unsigned short* Bt = (side ? PremT : HypT) + (size_t)b * 512 * 1024;
  const float* inv = (side ? colInv : rowInv) + b * 1024;
  const float* om  = (side ? hmask : pmask) + b * 1024;
  float* o = out + (size_t)side * NB * SLA * HH + (size_t)b * 1024 * 512;

  if (t < 128){
    sInv[t] = inv[m0 + t];
    sOM[t]  = om[m0 + t];
  }

  const int wv = t >> 6;
  const int L  = t & 63;
  const int lr = L >> 3;
  const int sw = L & 7;
  const int gkc = (sw ^ lr) * 8;

  const int lane = t & 63;
  const int wr = (t >> 7) & 1;
  const int wc = (t >> 6) & 1;
  const int q  = lane >> 4;
  const int ln = lane & 15;
  const int fsw = ln & 7;

  f32x4 acc[4][4];
  #pragma unroll
  for (int mt = 0; mt < 4; ++mt)
    #pragma unroll
    for (int nt = 0; nt < 4; ++nt)
      acc[mt][nt] = (f32x4){0.f, 0.f, 0.f, 0.f};

  for (int k0 = 0; k0 < 1024; k0 += 64){
    __syncthreads();
    #pragma unroll
    for (int s = 0; s < 4; ++s){
      int row = wv * 32 + s * 8 + lr;
      gl2lds16(A  + (size_t)(m0 + row) * 1024 + k0 + gkc, &sA[row * 64 + sw * 8]);
      gl2lds16(Bt + (size_t)(n0 + row) * 1024 + k0 + gkc, &sB[row * 64 + sw * 8]);
    }
    __syncthreads();

    #pragma unroll
    for (int h = 0; h < 2; ++h){
      s16x8 af[4], bfr[4];
      #pragma unroll
      for (int mt = 0; mt < 4; ++mt){
        int r = wr * 64 + mt * 16 + ln;
        af[mt] = *(const s16x8*)&sA[r * 64 + (((h << 2) + q) ^ fsw) * 8];
      }
      #pragma unroll
      for (int nt = 0; nt < 4; ++nt){
        int r = wc * 64 + nt * 16 + ln;
        bfr[nt] = *(const s16x8*)&sB[r * 64 + (((h << 2) + q) ^ fsw) * 8];
      }
      #pragma unroll
      for (int mt = 0; mt < 4; ++mt)
        #pragma unroll
        for (int nt = 0; nt < 4; ++nt)
          acc[mt][nt] = __builtin_amdgcn_mfma_f32_16x16x32_bf16(af[mt], bfr[nt], acc[mt][nt], 0, 0, 0);
    }
  }

  #pragma unroll
  for (int mt = 0; mt < 4; ++mt)
    #pragma unroll
    for (int nt = 0; nt < 4; ++nt){
      int col = n0 + wc * 64 + nt * 16 + ln;
      #pragma unroll
      for (int rr = 0; rr < 4; ++rr){
        int rowL = wr * 64 + mt * 16 + q * 4 + rr;
        o[(size_t)(m0 + rowL) * 512 + col] = acc[mt][nt][rr] * sInv[rowL] * sOM[rowL];
      }
    }
}

// ---------------------------------------------------------------------------
extern "C" void kernel_launch(void* const* d_in, const int* in_sizes, int n_in,
                              void* d_out, int out_size, void* d_ws, size_t ws_size,
                              hipStream_t stream)
{
  const float* prem  = (const float*)d_in[0];
  const float* pmask = (const float*)d_in[1];
  const float* hyp   = (const float*)d_in[2];
  const float* hmask = (const float*)d_in[3];
  float* out = (float*)d_out;

  char* ws = (char*)d_ws;
  float*    sim     = (float*)(ws);
  unsigned* rowMaxU = (unsigned*)(ws + 67108864);
  float*    rowInv  = (float*)(ws + 67108864 + 1 * 65536);   // sums -> inverted
  unsigned* colMaxU = (unsigned*)(ws + 67108864 + 2 * 65536);
  float*    colInv  = (float*)(ws + 67108864 + 3 * 65536);   // sums -> inverted
  const size_t base2 = 67108864 + 4 * 65536 + 1048576;   // 68419584 (layout-stable)
  char* premD1 = (char*)(ws + base2);
  char* premD0 = (char*)(ws + base2 + 8388608);
  char* hypD1  = (char*)(ws + base2 + 16777216);
  char* hypD0  = (char*)(ws + base2 + 25165824);
  unsigned short* PremT = (unsigned short*)(ws + base2 + 33554432);
  unsigned short* HypT  = (unsigned short*)(ws + base2 + 50331648);
  // Pprem aliases the digit planes (dead after sim_v3b); Phyp in fresh space
  unsigned short* Pprem = (unsigned short*)(ws + base2);
  unsigned short* Phyp  = (unsigned short*)(ws + base2 + 67108864);
  const size_t need = base2 + 100663296;         // 169,082,880 (same as R1-R4)
  if (ws_size < need) return;

  init_kernel<<<dim3(64), 256, 0, stream>>>(rowMaxU, colMaxU, rowInv, colInv);
  cvt_kernel<<<dim3(8, 16, 32), 256, 0, stream>>>(prem, hyp, premD1, premD0,
                                                  hypD1, hypD0, PremT, HypT);
  sim_gemm_v3b_kernel<<<dim3(16, 8, NB), 256, 0, stream>>>(premD1, premD0,
                                                           hypD1, hypD0,
                                                           pmask, hmask, sim,
                                                           rowMaxU, colMaxU);
  build_p_kernel<<<dim3(16, 16, NB), 256, 0, stream>>>(sim, rowMaxU, colMaxU,
                                                       pmask, hmask, Pprem, Phyp,
                                                       rowInv, colInv);
  inv_kernel<<<dim3(128), 256, 0, stream>>>(rowInv, colInv);
  av_bf16_kernel<<<dim3(4, 8, 32), 256, 0, stream>>>(Pprem, Phyp, HypT, PremT,
                                                     rowInv, colInv, pmask, hmask, out);
}

// Round 6
// 220.290 us; speedup vs baseline: 1.9936x; 1.1978x over previous
//
#include <hip/hip_runtime.h>
#include <math.h>

#define NB   16
#define SLA  1024
#define SLB  1024
#define HH   512

typedef __attribute__((ext_vector_type(4))) float  f32x4;
typedef __attribute__((ext_vector_type(8))) short  s16x8;
typedef __attribute__((ext_vector_type(4))) int    i32x4;

#define QS    (6.5f / 127.f)
#define QINVS (127.f / 6.5f)

__device__ __forceinline__ unsigned short f2bf(float x){
  unsigned u = __float_as_uint(x);
  u += 0x7fffu + ((u >> 16) & 1u);
  return (unsigned short)(u >> 16);
}
__device__ __forceinline__ float bf2f(unsigned short h){
  return __uint_as_float(((unsigned)h) << 16);
}
// order-preserving float->uint key (monotone); atomicMax-able
__device__ __forceinline__ unsigned fkey(float f){
  unsigned u = __float_as_uint(f);
  return ((int)u < 0) ? ~u : (u | 0x80000000u);
}
__device__ __forceinline__ float funkey(unsigned k){
  return __uint_as_float((k & 0x80000000u) ? (k & 0x7fffffffu) : ~k);
}

// async global->LDS, 16B per lane. LDS dest must be wave-uniform base + lane*16.
__device__ __forceinline__ void gl2lds16(const void* g, void* l){
  __builtin_amdgcn_global_load_lds(
      (__attribute__((address_space(1))) unsigned int*)(unsigned long long)(size_t)g,
      (__attribute__((address_space(3))) unsigned int*)(unsigned int)(size_t)l,
      16, 0, 0);
}

// ---------------------------------------------------------------------------
// init: zero sum accumulators and max keys (key 0 < key(any real))
// ---------------------------------------------------------------------------
__global__ __launch_bounds__(256) void init_kernel(
    unsigned* __restrict__ rowMaxU, unsigned* __restrict__ colMaxU,
    float* __restrict__ rowSum, float* __restrict__ colSum)
{
  const int g = blockIdx.x * 256 + threadIdx.x;   // 16384
  rowMaxU[g] = 0u; colMaxU[g] = 0u;
  rowSum[g] = 0.f; colSum[g] = 0.f;
}

// ---------------------------------------------------------------------------
// scan: per (batch, mask) compacted index list + count + count padded to 128
// ---------------------------------------------------------------------------
__global__ __launch_bounds__(256) void scan_kernel(
    const float* __restrict__ pmask, const float* __restrict__ hmask,
    int* __restrict__ pIdx, int* __restrict__ hIdx,
    int* __restrict__ pCnt, int* __restrict__ hCnt,
    int* __restrict__ pPad, int* __restrict__ hPad)
{
  __shared__ int ps[256];
  const int b     = blockIdx.x;
  const int which = blockIdx.y;
  const int t     = threadIdx.x;
  const float* m = (which ? hmask : pmask) + b * 1024;
  int* idx = (which ? hIdx : pIdx) + b * 1024;
  int* cnt = which ? hCnt : pCnt;
  int* pad = which ? hPad : pPad;

  int f[4], s = 0;
  #pragma unroll
  for (int e = 0; e < 4; ++e){
    f[e] = m[t * 4 + e] > 0.5f ? 1 : 0;
    s += f[e];
  }
  ps[t] = s;
  __syncthreads();
  for (int off = 1; off < 256; off <<= 1){
    int v = (t >= off) ? ps[t - off] : 0;
    __syncthreads();
    ps[t] += v;
    __syncthreads();
  }
  int pos = ps[t] - s;   // exclusive prefix of this thread's chunk
  #pragma unroll
  for (int e = 0; e < 4; ++e){
    if (f[e]) idx[pos++] = t * 4 + e;
  }
  if (t == 0){
    int total = ps[255];
    cnt[b] = total;
    pad[b] = (total + 127) & ~127;
  }
}

// ---------------------------------------------------------------------------
// zero_out: zero the masked-out output rows (harness poisons d_out)
// ---------------------------------------------------------------------------
__global__ __launch_bounds__(256) void zero_out_kernel(
    const float* __restrict__ pmask, const float* __restrict__ hmask,
    float* __restrict__ out)
{
  const int r = blockIdx.x * 4 + (threadIdx.x >> 6);   // 0..32767
  const int side = r >> 14;
  const int b    = (r >> 10) & 15;
  const int row  = r & 1023;
  const float mv = (side ? hmask : pmask)[b * 1024 + row];
  if (mv > 0.5f) return;
  float4 z = {0.f, 0.f, 0.f, 0.f};
  float* p = out + (size_t)side * NB * SLA * HH
                 + ((size_t)b * 1024 + row) * 512 + (threadIdx.x & 63) * 8;
  *(float4*)p = z;
  *(float4*)(p + 4) = z;
}

// ---------------------------------------------------------------------------
// cvt_gather: gather masked-in rows of X fp32 -> i8 digit planes (compact rows)
//             + bf16 transposed XT [b][512][cpad] (zeros in pad fringe)
// blockIdx.z = b + 16*tensor
// ---------------------------------------------------------------------------
__global__ __launch_bounds__(256) void cvt_gather_kernel(
    const float* __restrict__ prem, const float* __restrict__ hyp,
    const int* __restrict__ pIdx, const int* __restrict__ hIdx,
    const int* __restrict__ pCnt, const int* __restrict__ hCnt,
    const int* __restrict__ pPad, const int* __restrict__ hPad,
    char* __restrict__ premD1, char* __restrict__ premD0,
    char* __restrict__ hypD1,  char* __restrict__ hypD0,
    unsigned short* __restrict__ PremT, unsigned short* __restrict__ HypT)
{
  __shared__ unsigned short tv[64][72];
  __shared__ int sIdx[64];

  const int tensor = blockIdx.z >> 4;
  const int b  = blockIdx.z & 15;
  const int l0 = blockIdx.y * 64;     // compact-row tile
  const int h0 = blockIdx.x * 64;
  const int t  = threadIdx.x;

  const int cnt = tensor ? hCnt[b] : pCnt[b];
  const int pad = tensor ? hPad[b] : pPad[b];
  if (l0 >= pad) return;

  const float* X = tensor ? hyp : prem;
  const int* idx = (tensor ? hIdx : pIdx) + b * 1024;
  char* D1 = tensor ? hypD1 : premD1;
  char* D0 = tensor ? hypD0 : premD0;
  unsigned short* XT = tensor ? HypT : PremT;

  if (t < 64){
    int jc = l0 + t;
    sIdx[t] = (jc < cnt) ? idx[jc] : -1;
  }
  __syncthreads();

  #pragma unroll
  for (int it = 0; it < 4; ++it){
    int r = (t >> 4) + it * 16;        // compact-row local
    int c = (t & 15) * 4;              // h local
    int orig = sIdx[r];
    float4 x = {0.f, 0.f, 0.f, 0.f};
    if (orig >= 0)
      x = *(const float4*)(X + ((size_t)b * 1024 + orig) * HH + h0 + c);
    float xv[4] = {x.x, x.y, x.z, x.w};
    char d1v[4], d0v[4];
    #pragma unroll
    for (int e = 0; e < 4; ++e){
      float xs = xv[e] * QINVS;
      float x1 = rintf(xs);
      x1 = fminf(127.f, fmaxf(-127.f, x1));
      float x0 = rintf((xs - x1) * 256.f);
      x0 = fminf(127.f, fmaxf(-128.f, x0));
      d1v[e] = (char)(int)x1;
      d0v[e] = (char)(int)x0;
      tv[c + e][r] = f2bf(xv[e]);
    }
    size_t go = ((size_t)b * 1024 + l0 + r) * HH + h0 + c;
    *(char4*)(D1 + go) = make_char4(d1v[0], d1v[1], d1v[2], d1v[3]);
    *(char4*)(D0 + go) = make_char4(d0v[0], d0v[1], d0v[2], d0v[3]);
  }
  __syncthreads();
  const int w   = t >> 2;
  const int seg = (t & 3) * 16;
  const uint4* src = (const uint4*)&tv[w][seg];
  uint4* dst = (uint4*)(XT + ((size_t)b * HH + h0 + w) * 1024 + l0 + seg);
  dst[0] = src[0];
  dst[1] = src[1];
}

// ---------------------------------------------------------------------------
// sim_v4: compacted i8 GEMM. sim_c[ic][jc] = s^2*(D1 + Dc/256).
// Block tile 128(M)x64(N), BK=64, wave tile 64x32. Fused max epilogue with
// count guards (no masks — compacted rows are all valid).
// ---------------------------------------------------------------------------
__global__ __launch_bounds__(256, 3) void sim_gemm_v4_kernel(
    const char* __restrict__ premD1, const char* __restrict__ premD0,
    const char* __restrict__ hypD1,  const char* __restrict__ hypD0,
    const int* __restrict__ pCnt, const int* __restrict__ hCnt,
    const int* __restrict__ pPad, const int* __restrict__ hPad,
    float* __restrict__ sim,
    unsigned* __restrict__ rowMaxU, unsigned* __restrict__ colMaxU)
{
  __shared__ char sA1[128 * 64];
  __shared__ char sA0[128 * 64];
  __shared__ char sB1[64 * 64];
  __shared__ char sB0[64 * 64];

  const int b  = blockIdx.z;
  const int i0 = blockIdx.y * 128;
  const int j0 = blockIdx.x * 64;
  const int t  = threadIdx.x;

  const int pc = pCnt[b], hc = hCnt[b];
  if (i0 >= pPad[b] || j0 >= hPad[b]) return;

  const char* A1 = premD1 + ((size_t)b * 1024 + i0) * HH;
  const char* A0 = premD0 + ((size_t)b * 1024 + i0) * HH;
  const char* B1 = hypD1  + ((size_t)b * 1024 + j0) * HH;
  const char* B0 = hypD0  + ((size_t)b * 1024 + j0) * HH;

  const int sr = t >> 2;                            // 0..63
  const int gc = ((t & 3) ^ (sr & 3)) * 16;         // swizzled global chunk (bytes)
  const int lco = (t & 3) * 16;

  const int lane = t & 63;
  const int wr = (t >> 7) & 1;      // M half
  const int wc = (t >> 6) & 1;      // N half
  const int q  = lane >> 4;
  const int ln = lane & 15;
  const int fo = (q ^ (ln & 3)) * 16;   // frag-read chunk offset (bytes)

  i32x4 acc1[4][2], accc[4][2];
  #pragma unroll
  for (int mt = 0; mt < 4; ++mt)
    #pragma unroll
    for (int nt = 0; nt < 2; ++nt){
      acc1[mt][nt] = (i32x4){0, 0, 0, 0};
      accc[mt][nt] = (i32x4){0, 0, 0, 0};
    }

  for (int k0 = 0; k0 < HH; k0 += 64){
    __syncthreads();
    {
      const size_t goA = (size_t)sr * HH + k0 + gc;
      gl2lds16(A1 + goA, &sA1[sr * 64 + lco]);
      gl2lds16(A0 + goA, &sA0[sr * 64 + lco]);
      const size_t goA2 = (size_t)(64 + sr) * HH + k0 + gc;
      gl2lds16(A1 + goA2, &sA1[(64 + sr) * 64 + lco]);
      gl2lds16(A0 + goA2, &sA0[(64 + sr) * 64 + lco]);
      gl2lds16(B1 + goA, &sB1[sr * 64 + lco]);
      gl2lds16(B0 + goA, &sB0[sr * 64 + lco]);
    }
    __syncthreads();

    i32x4 af[4], bf1[2], bf0[2];
    #pragma unroll
    for (int mt = 0; mt < 4; ++mt)
      af[mt] = *(const i32x4*)&sA1[(wr * 64 + mt * 16 + ln) * 64 + fo];
    #pragma unroll
    for (int nt = 0; nt < 2; ++nt)
      bf1[nt] = *(const i32x4*)&sB1[(wc * 32 + nt * 16 + ln) * 64 + fo];
    #pragma unroll
    for (int mt = 0; mt < 4; ++mt)
      #pragma unroll
      for (int nt = 0; nt < 2; ++nt)
        acc1[mt][nt] = __builtin_amdgcn_mfma_i32_16x16x64_i8(af[mt], bf1[nt], acc1[mt][nt], 0, 0, 0);
    #pragma unroll
    for (int nt = 0; nt < 2; ++nt)
      bf0[nt] = *(const i32x4*)&sB0[(wc * 32 + nt * 16 + ln) * 64 + fo];
    #pragma unroll
    for (int mt = 0; mt < 4; ++mt)
      #pragma unroll
      for (int nt = 0; nt < 2; ++nt)
        accc[mt][nt] = __builtin_amdgcn_mfma_i32_16x16x64_i8(af[mt], bf0[nt], accc[mt][nt], 0, 0, 0);
    #pragma unroll
    for (int mt = 0; mt < 4; ++mt)
      af[mt] = *(const i32x4*)&sA0[(wr * 64 + mt * 16 + ln) * 64 + fo];
    #pragma unroll
    for (int mt = 0; mt < 4; ++mt)
      #pragma unroll
      for (int nt = 0; nt < 2; ++nt)
        accc[mt][nt] = __builtin_amdgcn_mfma_i32_16x16x64_i8(af[mt], bf1[nt], accc[mt][nt], 0, 0, 0);
  }

  // epilogue: sim write + fused row/col max (count guards)
  const float S2 = QS * QS;
  float* simb = sim + ((size_t)b * SLA + i0) * SLB + j0;

  float rmx[16];
  #pragma unroll
  for (int e = 0; e < 16; ++e) rmx[e] = -1e30f;
  float cmx[2];
  cmx[0] = -1e30f; cmx[1] = -1e30f;

  #pragma unroll
  for (int mt = 0; mt < 4; ++mt){
    #pragma unroll
    for (int nt = 0; nt < 2; ++nt){
      int col = wc * 32 + nt * 16 + ln;
      bool colv = (j0 + col) < hc;
      #pragma unroll
      for (int rr = 0; rr < 4; ++rr){
        int row = wr * 64 + mt * 16 + q * 4 + rr;
        float f = S2 * ((float)acc1[mt][nt][rr] + (float)accc[mt][nt][rr] * 0.00390625f);
        simb[(size_t)row * SLB + col] = f;
        rmx[mt * 4 + rr] = fmaxf(rmx[mt * 4 + rr], colv ? f : -1e30f);
        cmx[nt] = fmaxf(cmx[nt], (i0 + row) < pc ? f : -1e30f);
      }
    }
  }

  #pragma unroll
  for (int e = 0; e < 16; ++e){
    float v = rmx[e];
    v = fmaxf(v, __shfl_xor(v, 1));
    v = fmaxf(v, __shfl_xor(v, 2));
    v = fmaxf(v, __shfl_xor(v, 4));
    v = fmaxf(v, __shfl_xor(v, 8));
    if (ln == 0){
      int row = wr * 64 + (e >> 2) * 16 + q * 4 + (e & 3);
      if (i0 + row < pc)
        atomicMax(rowMaxU + b * 1024 + i0 + row, fkey(v));
    }
  }
  #pragma unroll
  for (int nt = 0; nt < 2; ++nt){
    float v = cmx[nt];
    v = fmaxf(v, __shfl_xor(v, 16));
    v = fmaxf(v, __shfl_xor(v, 32));
    if (q == 0){
      int col = wc * 32 + nt * 16 + ln;
      if (j0 + col < hc)
        atomicMax(colMaxU + b * 1024 + j0 + col, fkey(v));
    }
  }
}

// ---------------------------------------------------------------------------
// inv: x -> 1/x in place
// ---------------------------------------------------------------------------
__global__ __launch_bounds__(256) void inv_kernel(float* __restrict__ rowS,
                                                  float* __restrict__ colS)
{
  const int g = blockIdx.x * 256 + threadIdx.x;
  if (g < 16384)      rowS[g] = 1.f / rowS[g];
  else                colS[g - 16384] = 1.f / colS[g - 16384];
}

// ---------------------------------------------------------------------------
// build_p_v4 (compacted): Pprem[ic][jc] = exp(sim-rowMax[ic]) (direct)
//                          Phyp[jc][ic] = exp(sim-colMax[jc]) (transposed)
// Count-guards zero the pad fringe. Row/col sums via shfl + atomicAdd.
// ---------------------------------------------------------------------------
__global__ __launch_bounds__(256) void build_p_v4_kernel(
    const float* __restrict__ sim,
    const unsigned* __restrict__ rowMaxU, const unsigned* __restrict__ colMaxU,
    const int* __restrict__ pCnt, const int* __restrict__ hCnt,
    const int* __restrict__ pPad, const int* __restrict__ hPad,
    unsigned short* __restrict__ Pprem, unsigned short* __restrict__ Phyp,
    float* __restrict__ rowSumAcc, float* __restrict__ colSumAcc)
{
  __shared__ unsigned short tp[64][72];
  __shared__ float sRM[64], sCM[64];

  const int b  = blockIdx.z;
  const int i0 = blockIdx.y * 64;
  const int j0 = blockIdx.x * 64;
  const int t  = threadIdx.x;

  const int pc = pCnt[b], hc = hCnt[b];
  if (i0 >= pPad[b] || j0 >= hPad[b]) return;

  {
    int which = t >> 6, idx = t & 63;
    if (which == 0) sRM[idx] = funkey(rowMaxU[b * 1024 + i0 + idx]);
    if (which == 1) sCM[idx] = funkey(colMaxU[b * 1024 + j0 + idx]);
  }
  __syncthreads();

  const float* sb = sim + (size_t)b * SLA * SLB;
  #pragma unroll
  for (int it = 0; it < 4; ++it){
    int r = (t >> 4) + it * 16;        // ic local
    int c = (t & 15) * 4;              // jc local
    float4 s = *(const float4*)(sb + (size_t)(i0 + r) * SLB + j0 + c);
    float rm = sRM[r];
    bool vi = (i0 + r) < pc;
    float p0 = (vi && (j0 + c + 0) < hc) ? __expf(s.x - rm) : 0.f;
    float p1 = (vi && (j0 + c + 1) < hc) ? __expf(s.y - rm) : 0.f;
    float p2 = (vi && (j0 + c + 2) < hc) ? __expf(s.z - rm) : 0.f;
    float p3 = (vi && (j0 + c + 3) < hc) ? __expf(s.w - rm) : 0.f;
    uint2 pk;
    pk.x = (unsigned)f2bf(p0) | ((unsigned)f2bf(p1) << 16);
    pk.y = (unsigned)f2bf(p2) | ((unsigned)f2bf(p3) << 16);
    *(uint2*)(Pprem + ((size_t)b * 1024 + i0 + r) * 1024 + j0 + c) = pk;

    float rs = p0 + p1 + p2 + p3;
    rs += __shfl_xor(rs, 1);
    rs += __shfl_xor(rs, 2);
    rs += __shfl_xor(rs, 4);
    rs += __shfl_xor(rs, 8);
    if ((t & 15) == 0 && vi)
      atomicAdd(rowSumAcc + b * 1024 + i0 + r, rs);

    tp[c + 0][r] = f2bf((vi && (j0 + c + 0) < hc) ? __expf(s.x - sCM[c+0]) : 0.f);
    tp[c + 1][r] = f2bf((vi && (j0 + c + 1) < hc) ? __expf(s.y - sCM[c+1]) : 0.f);
    tp[c + 2][r] = f2bf((vi && (j0 + c + 2) < hc) ? __expf(s.z - sCM[c+2]) : 0.f);
    tp[c + 3][r] = f2bf((vi && (j0 + c + 3) < hc) ? __expf(s.w - sCM[c+3]) : 0.f);
  }
  __syncthreads();
  const int w   = t >> 2;              // jc local
  const int seg = (t & 3) * 16;        // ic local
  const uint4* src = (const uint4*)&tp[w][seg];
  uint4 u0 = src[0], u1 = src[1];
  uint4* dst = (uint4*)(Phyp + ((size_t)b * 1024 + j0 + w) * 1024 + i0 + seg);
  dst[0] = u0;
  dst[1] = u1;

  const unsigned short* us0 = (const unsigned short*)&u0;
  const unsigned short* us1 = (const unsigned short*)&u1;
  float cs = 0.f;
  #pragma unroll
  for (int e = 0; e < 8; ++e) cs += bf2f(us0[e]);
  #pragma unroll
  for (int e = 0; e < 8; ++e) cs += bf2f(us1[e]);
  cs += __shfl_xor(cs, 1);
  cs += __shfl_xor(cs, 2);
  if ((t & 3) == 0 && (j0 + w) < hc)
    atomicAdd(colSumAcc + b * 1024 + j0 + w, cs);
}

// ---------------------------------------------------------------------------
// av_v4 (compacted): out[orig(m)][n] = Inv[m] * sum_k A[m][k]*Bt[n][k]
// K loop bound = other side's pad; scatter rows via index list.
// blockIdx.z = b + 16*side.
// ---------------------------------------------------------------------------
__global__ __launch_bounds__(256) void av_v4_kernel(
    const unsigned short* __restrict__ Pprem, const unsigned short* __restrict__ Phyp,
    const unsigned short* __restrict__ HypT,  const unsigned short* __restrict__ PremT,
    const float* __restrict__ rowInv, const float* __restrict__ colInv,
    const int* __restrict__ pIdx, const int* __restrict__ hIdx,
    const int* __restrict__ pCnt, const int* __restrict__ hCnt,
    const int* __restrict__ pPad, const int* __restrict__ hPad,
    float* __restrict__ out)
{
  __shared__ unsigned short sA[128 * 64];
  __shared__ unsigned short sB[128 * 64];
  __shared__ float sInv[128];
  __shared__ int sIdx[128];

  const int side = blockIdx.z >> 4;
  const int b    = blockIdx.z & 15;
  const int m0   = blockIdx.y * 128;
  const int n0   = blockIdx.x * 128;
  const int t    = threadIdx.x;

  const int cnt  = side ? hCnt[b] : pCnt[b];
  const int mpad = side ? hPad[b] : pPad[b];
  const int kpad = side ? pPad[b] : hPad[b];
  if (m0 >= mpad) return;

  const unsigned short* A  = (side ? Phyp : Pprem) + (size_t)b * 1024 * 1024;
  const unsigned short* Bt = (side ? PremT : HypT) + (size_t)b * 512 * 1024;
  const float* inv = (side ? colInv : rowInv) + b * 1024;
  const int* idx   = (side ? hIdx : pIdx) + b * 1024;
  float* o = out + (size_t)side * NB * SLA * HH + (size_t)b * 1024 * 512;

  if (t < 128){
    sInv[t] = inv[m0 + t];
    sIdx[t] = idx[m0 + t];
  }

  const int wv = t >> 6;
  const int L  = t & 63;
  const int lr = L >> 3;
  const int sw = L & 7;
  const int gkc = (sw ^ lr) * 8;

  const int lane = t & 63;
  const int wr = (t >> 7) & 1;
  const int wc = (t >> 6) & 1;
  const int q  = lane >> 4;
  const int ln = lane & 15;
  const int fsw = ln & 7;

  f32x4 acc[4][4];
  #pragma unroll
  for (int mt = 0; mt < 4; ++mt)
    #pragma unroll
    for (int nt = 0; nt < 4; ++nt)
      acc[mt][nt] = (f32x4){0.f, 0.f, 0.f, 0.f};

  for (int k0 = 0; k0 < kpad; k0 += 64){
    __syncthreads();
    #pragma unroll
    for (int s = 0; s < 4; ++s){
      int row = wv * 32 + s * 8 + lr;
      gl2lds16(A  + (size_t)(m0 + row) * 1024 + k0 + gkc, &sA[row * 64 + sw * 8]);
      gl2lds16(Bt + (size_t)(n0 + row) * 1024 + k0 + gkc, &sB[row * 64 + sw * 8]);
    }
    __syncthreads();

    #pragma unroll
    for (int h = 0; h < 2; ++h){
      s16x8 af[4], bfr[4];
      #pragma unroll
      for (int mt = 0; mt < 4; ++mt){
        int r = wr * 64 + mt * 16 + ln;
        af[mt] = *(const s16x8*)&sA[r * 64 + (((h << 2) + q) ^ fsw) * 8];
      }
      #pragma unroll
      for (int nt = 0; nt < 4; ++nt){
        int r = wc * 64 + nt * 16 + ln;
        bfr[nt] = *(const s16x8*)&sB[r * 64 + (((h << 2) + q) ^ fsw) * 8];
      }
      #pragma unroll
      for (int mt = 0; mt < 4; ++mt)
        #pragma unroll
        for (int nt = 0; nt < 4; ++nt)
          acc[mt][nt] = __builtin_amdgcn_mfma_f32_16x16x32_bf16(af[mt], bfr[nt], acc[mt][nt], 0, 0, 0);
    }
  }

  #pragma unroll
  for (int mt = 0; mt < 4; ++mt)
    #pragma unroll
    for (int nt = 0; nt < 4; ++nt){
      int col = n0 + wc * 64 + nt * 16 + ln;
      #pragma unroll
      for (int rr = 0; rr < 4; ++rr){
        int rowL = wr * 64 + mt * 16 + q * 4 + rr;
        if (m0 + rowL < cnt)
          o[(size_t)sIdx[rowL] * 512 + col] = acc[mt][nt][rr] * sInv[rowL];
      }
    }
}

// ---------------------------------------------------------------------------
extern "C" void kernel_launch(void* const* d_in, const int* in_sizes, int n_in,
                              void* d_out, int out_size, void* d_ws, size_t ws_size,
                              hipStream_t stream)
{
  const float* prem  = (const float*)d_in[0];
  const float* pmask = (const float*)d_in[1];
  const float* hyp   = (const float*)d_in[2];
  const float* hmask = (const float*)d_in[3];
  float* out = (float*)d_out;

  char* ws = (char*)d_ws;
  float*    sim     = (float*)(ws);
  unsigned* rowMaxU = (unsigned*)(ws + 67108864);
  float*    rowInv  = (float*)(ws + 67108864 + 1 * 65536);   // sums -> inverted
  unsigned* colMaxU = (unsigned*)(ws + 67108864 + 2 * 65536);
  float*    colInv  = (float*)(ws + 67108864 + 3 * 65536);   // sums -> inverted
  int* pIdx = (int*)(ws + 67108864 + 4 * 65536);
  int* hIdx = (int*)(ws + 67108864 + 5 * 65536);
  int* pCnt = (int*)(ws + 67108864 + 6 * 65536);
  int* hCnt = (int*)(ws + 67108864 + 6 * 65536 + 256);
  int* pPad = (int*)(ws + 67108864 + 6 * 65536 + 512);
  int* hPad = (int*)(ws + 67108864 + 6 * 65536 + 768);
  const size_t base2 = 67108864 + 4 * 65536 + 1048576;   // 68419584 (layout-stable)
  char* premD1 = (char*)(ws + base2);
  char* premD0 = (char*)(ws + base2 + 8388608);
  char* hypD1  = (char*)(ws + base2 + 16777216);
  char* hypD0  = (char*)(ws + base2 + 25165824);
  unsigned short* PremT = (unsigned short*)(ws + base2 + 33554432);
  unsigned short* HypT  = (unsigned short*)(ws + base2 + 50331648);
  // Pprem aliases the digit planes (dead after sim_v4); Phyp in fresh space
  unsigned short* Pprem = (unsigned short*)(ws + base2);
  unsigned short* Phyp  = (unsigned short*)(ws + base2 + 67108864);
  const size_t need = base2 + 100663296;         // 169,082,880 (same as R1-R5)
  if (ws_size < need) return;

  init_kernel<<<dim3(64), 256, 0, stream>>>(rowMaxU, colMaxU, rowInv, colInv);
  scan_kernel<<<dim3(16, 2), 256, 0, stream>>>(pmask, hmask, pIdx, hIdx,
                                               pCnt, hCnt, pPad, hPad);
  zero_out_kernel<<<dim3(8192), 256, 0, stream>>>(pmask, hmask, out);
  cvt_gather_kernel<<<dim3(8, 16, 32), 256, 0, stream>>>(
      prem, hyp, pIdx, hIdx, pCnt, hCnt, pPad, hPad,
      premD1, premD0, hypD1, hypD0, PremT, HypT);
  sim_gemm_v4_kernel<<<dim3(16, 8, NB), 256, 0, stream>>>(
      premD1, premD0, hypD1, hypD0, pCnt, hCnt, pPad, hPad,
      sim, rowMaxU, colMaxU);
  build_p_v4_kernel<<<dim3(16, 16, NB), 256, 0, stream>>>(
      sim, rowMaxU, colMaxU, pCnt, hCnt, pPad, hPad,
      Pprem, Phyp, rowInv, colInv);
  inv_kernel<<<dim3(128), 256, 0, stream>>>(rowInv, colInv);
  av_v4_kernel<<<dim3(4, 8, 32), 256, 0, stream>>>(
      Pprem, Phyp, HypT, PremT, rowInv, colInv,
      pIdx, hIdx, pCnt, hCnt, pPad, hPad, out);
}

// Round 7
// 209.299 us; speedup vs baseline: 2.0983x; 1.0525x over previous
//
#include <hip/hip_runtime.h>
#include <hip/hip_fp16.h>
#include <math.h>

#define NB   16
#define SLA  1024
#define SLB  1024
#define HH   512

typedef __attribute__((ext_vector_type(4))) float  f32x4;
typedef __attribute__((ext_vector_type(8))) short  s16x8;
typedef __attribute__((ext_vector_type(4))) int    i32x4;

#define QS    (6.5f / 127.f)
#define QINVS (127.f / 6.5f)

__device__ __forceinline__ unsigned short f2bf(float x){
  unsigned u = __float_as_uint(x);
  u += 0x7fffu + ((u >> 16) & 1u);
  return (unsigned short)(u >> 16);
}
__device__ __forceinline__ float bf2f(unsigned short h){
  return __uint_as_float(((unsigned)h) << 16);
}
__device__ __forceinline__ float h2f(unsigned short h){
  return __half2float(__ushort_as_half(h));
}
// order-preserving float->uint key (monotone); atomicMax-able
__device__ __forceinline__ unsigned fkey(float f){
  unsigned u = __float_as_uint(f);
  return ((int)u < 0) ? ~u : (u | 0x80000000u);
}
__device__ __forceinline__ float funkey(unsigned k){
  return __uint_as_float((k & 0x80000000u) ? (k & 0x7fffffffu) : ~k);
}

// async global->LDS, 16B per lane. LDS dest must be wave-uniform base + lane*16.
__device__ __forceinline__ void gl2lds16(const void* g, void* l){
  __builtin_amdgcn_global_load_lds(
      (__attribute__((address_space(1))) unsigned int*)(unsigned long long)(size_t)g,
      (__attribute__((address_space(3))) unsigned int*)(unsigned int)(size_t)l,
      16, 0, 0);
}

// ---------------------------------------------------------------------------
// scan: per (batch, mask) compacted index list + counts; also zeroes the
// max-key / sum accumulators for this (b, which).
// ---------------------------------------------------------------------------
__global__ __launch_bounds__(256) void scan_kernel(
    const float* __restrict__ pmask, const float* __restrict__ hmask,
    int* __restrict__ pIdx, int* __restrict__ hIdx,
    int* __restrict__ pCnt, int* __restrict__ hCnt,
    int* __restrict__ pPad, int* __restrict__ hPad,
    unsigned* __restrict__ rowMaxU, unsigned* __restrict__ colMaxU,
    float* __restrict__ colSum)
{
  __shared__ int ps[256];
  const int b     = blockIdx.x;
  const int which = blockIdx.y;
  const int t     = threadIdx.x;
  const float* m = (which ? hmask : pmask) + b * 1024;
  int* idx = (which ? hIdx : pIdx) + b * 1024;
  int* cnt = which ? hCnt : pCnt;
  int* pad = which ? hPad : pPad;

  // zero accumulators (independent of scan)
  #pragma unroll
  for (int v = 0; v < 4; ++v){
    int g = b * 1024 + t + v * 256;
    if (which == 0){
      rowMaxU[g] = 0u;
    } else {
      colMaxU[g] = 0u;
      colSum[g]  = 0.f;
    }
  }

  int f[4], s = 0;
  #pragma unroll
  for (int e = 0; e < 4; ++e){
    f[e] = m[t * 4 + e] > 0.5f ? 1 : 0;
    s += f[e];
  }
  ps[t] = s;
  __syncthreads();
  for (int off = 1; off < 256; off <<= 1){
    int v = (t >= off) ? ps[t - off] : 0;
    __syncthreads();
    ps[t] += v;
    __syncthreads();
  }
  int pos = ps[t] - s;
  #pragma unroll
  for (int e = 0; e < 4; ++e){
    if (f[e]) idx[pos++] = t * 4 + e;
  }
  if (t == 0){
    int total = ps[255];
    cnt[b] = total;
    pad[b] = (total + 127) & ~127;
  }
}

// ---------------------------------------------------------------------------
// zero_out: zero the masked-out output rows (harness poisons d_out)
// ---------------------------------------------------------------------------
__global__ __launch_bounds__(256) void zero_out_kernel(
    const float* __restrict__ pmask, const float* __restrict__ hmask,
    float* __restrict__ out)
{
  const int r = blockIdx.x * 4 + (threadIdx.x >> 6);   // 0..32767
  const int side = r >> 14;
  const int b    = (r >> 10) & 15;
  const int row  = r & 1023;
  const float mv = (side ? hmask : pmask)[b * 1024 + row];
  if (mv > 0.5f) return;
  float4 z = {0.f, 0.f, 0.f, 0.f};
  float* p = out + (size_t)side * NB * SLA * HH
                 + ((size_t)b * 1024 + row) * 512 + (threadIdx.x & 63) * 8;
  *(float4*)p = z;
  *(float4*)(p + 4) = z;
}

// ---------------------------------------------------------------------------
// cvt_gather: gather masked-in rows -> i8 digit planes (compact) + bf16
// transposed XT [b][512][1024] (zeros in pad fringe). blockIdx.z = b+16*tensor
// ---------------------------------------------------------------------------
__global__ __launch_bounds__(256) void cvt_gather_kernel(
    const float* __restrict__ prem, const float* __restrict__ hyp,
    const int* __restrict__ pIdx, const int* __restrict__ hIdx,
    const int* __restrict__ pCnt, const int* __restrict__ hCnt,
    const int* __restrict__ pPad, const int* __restrict__ hPad,
    char* __restrict__ premD1, char* __restrict__ premD0,
    char* __restrict__ hypD1,  char* __restrict__ hypD0,
    unsigned short* __restrict__ PremT, unsigned short* __restrict__ HypT)
{
  __shared__ unsigned short tv[64][72];
  __shared__ int sIdx[64];

  const int tensor = blockIdx.z >> 4;
  const int b  = blockIdx.z & 15;
  const int l0 = blockIdx.y * 64;
  const int h0 = blockIdx.x * 64;
  const int t  = threadIdx.x;

  const int cnt = tensor ? hCnt[b] : pCnt[b];
  const int pad = tensor ? hPad[b] : pPad[b];
  if (l0 >= pad) return;

  const float* X = tensor ? hyp : prem;
  const int* idx = (tensor ? hIdx : pIdx) + b * 1024;
  char* D1 = tensor ? hypD1 : premD1;
  char* D0 = tensor ? hypD0 : premD0;
  unsigned short* XT = tensor ? HypT : PremT;

  if (t < 64){
    int jc = l0 + t;
    sIdx[t] = (jc < cnt) ? idx[jc] : -1;
  }
  __syncthreads();

  #pragma unroll
  for (int it = 0; it < 4; ++it){
    int r = (t >> 4) + it * 16;
    int c = (t & 15) * 4;
    int orig = sIdx[r];
    float4 x = {0.f, 0.f, 0.f, 0.f};
    if (orig >= 0)
      x = *(const float4*)(X + ((size_t)b * 1024 + orig) * HH + h0 + c);
    float xv[4] = {x.x, x.y, x.z, x.w};
    char d1v[4], d0v[4];
    #pragma unroll
    for (int e = 0; e < 4; ++e){
      float xs = xv[e] * QINVS;
      float x1 = rintf(xs);
      x1 = fminf(127.f, fmaxf(-127.f, x1));
      float x0 = rintf((xs - x1) * 256.f);
      x0 = fminf(127.f, fmaxf(-128.f, x0));
      d1v[e] = (char)(int)x1;
      d0v[e] = (char)(int)x0;
      tv[c + e][r] = f2bf(xv[e]);
    }
    size_t go = ((size_t)b * 1024 + l0 + r) * HH + h0 + c;
    *(char4*)(D1 + go) = make_char4(d1v[0], d1v[1], d1v[2], d1v[3]);
    *(char4*)(D0 + go) = make_char4(d0v[0], d0v[1], d0v[2], d0v[3]);
  }
  __syncthreads();
  const int w   = t >> 2;
  const int seg = (t & 3) * 16;
  const uint4* src = (const uint4*)&tv[w][seg];
  uint4* dst = (uint4*)(XT + ((size_t)b * HH + h0 + w) * 1024 + l0 + seg);
  dst[0] = src[0];
  dst[1] = src[1];
}

// ---------------------------------------------------------------------------
// sim_v5: compacted i8 GEMM -> sim fp16. Block 128(M)x64(N), BK=64, wave 64x32.
// Fused epilogue: masked row/col max -> atomicMax on uint keys.
// ---------------------------------------------------------------------------
__global__ __launch_bounds__(256, 3) void sim_gemm_v5_kernel(
    const char* __restrict__ premD1, const char* __restrict__ premD0,
    const char* __restrict__ hypD1,  const char* __restrict__ hypD0,
    const int* __restrict__ pCnt, const int* __restrict__ hCnt,
    const int* __restrict__ pPad, const int* __restrict__ hPad,
    unsigned short* __restrict__ simH,
    unsigned* __restrict__ rowMaxU, unsigned* __restrict__ colMaxU)
{
  __shared__ char sA1[128 * 64];
  __shared__ char sA0[128 * 64];
  __shared__ char sB1[64 * 64];
  __shared__ char sB0[64 * 64];

  const int b  = blockIdx.z;
  const int i0 = blockIdx.y * 128;
  const int j0 = blockIdx.x * 64;
  const int t  = threadIdx.x;

  const int pc = pCnt[b], hc = hCnt[b];
  if (i0 >= pPad[b] || j0 >= hPad[b]) return;

  const char* A1 = premD1 + ((size_t)b * 1024 + i0) * HH;
  const char* A0 = premD0 + ((size_t)b * 1024 + i0) * HH;
  const char* B1 = hypD1  + ((size_t)b * 1024 + j0) * HH;
  const char* B0 = hypD0  + ((size_t)b * 1024 + j0) * HH;

  const int sr = t >> 2;
  const int gc = ((t & 3) ^ (sr & 3)) * 16;
  const int lco = (t & 3) * 16;

  const int lane = t & 63;
  const int wr = (t >> 7) & 1;
  const int wc = (t >> 6) & 1;
  const int q  = lane >> 4;
  const int ln = lane & 15;
  const int fo = (q ^ (ln & 3)) * 16;

  i32x4 acc1[4][2], accc[4][2];
  #pragma unroll
  for (int mt = 0; mt < 4; ++mt)
    #pragma unroll
    for (int nt = 0; nt < 2; ++nt){
      acc1[mt][nt] = (i32x4){0, 0, 0, 0};
      accc[mt][nt] = (i32x4){0, 0, 0, 0};
    }

  for (int k0 = 0; k0 < HH; k0 += 64){
    __syncthreads();
    {
      const size_t goA = (size_t)sr * HH + k0 + gc;
      gl2lds16(A1 + goA, &sA1[sr * 64 + lco]);
      gl2lds16(A0 + goA, &sA0[sr * 64 + lco]);
      const size_t goA2 = (size_t)(64 + sr) * HH + k0 + gc;
      gl2lds16(A1 + goA2, &sA1[(64 + sr) * 64 + lco]);
      gl2lds16(A0 + goA2, &sA0[(64 + sr) * 64 + lco]);
      gl2lds16(B1 + goA, &sB1[sr * 64 + lco]);
      gl2lds16(B0 + goA, &sB0[sr * 64 + lco]);
    }
    __syncthreads();

    i32x4 af[4], bf1[2], bf0[2];
    #pragma unroll
    for (int mt = 0; mt < 4; ++mt)
      af[mt] = *(const i32x4*)&sA1[(wr * 64 + mt * 16 + ln) * 64 + fo];
    #pragma unroll
    for (int nt = 0; nt < 2; ++nt)
      bf1[nt] = *(const i32x4*)&sB1[(wc * 32 + nt * 16 + ln) * 64 + fo];
    #pragma unroll
    for (int mt = 0; mt < 4; ++mt)
      #pragma unroll
      for (int nt = 0; nt < 2; ++nt)
        acc1[mt][nt] = __builtin_amdgcn_mfma_i32_16x16x64_i8(af[mt], bf1[nt], acc1[mt][nt], 0, 0, 0);
    #pragma unroll
    for (int nt = 0; nt < 2; ++nt)
      bf0[nt] = *(const i32x4*)&sB0[(wc * 32 + nt * 16 + ln) * 64 + fo];
    #pragma unroll
    for (int mt = 0; mt < 4; ++mt)
      #pragma unroll
      for (int nt = 0; nt < 2; ++nt)
        accc[mt][nt] = __builtin_amdgcn_mfma_i32_16x16x64_i8(af[mt], bf0[nt], accc[mt][nt], 0, 0, 0);
    #pragma unroll
    for (int mt = 0; mt < 4; ++mt)
      af[mt] = *(const i32x4*)&sA0[(wr * 64 + mt * 16 + ln) * 64 + fo];
    #pragma unroll
    for (int mt = 0; mt < 4; ++mt)
      #pragma unroll
      for (int nt = 0; nt < 2; ++nt)
        accc[mt][nt] = __builtin_amdgcn_mfma_i32_16x16x64_i8(af[mt], bf1[nt], accc[mt][nt], 0, 0, 0);
  }

  const float S2 = QS * QS;
  unsigned short* simb = simH + ((size_t)b * SLA + i0) * SLB + j0;

  float rmx[16];
  #pragma unroll
  for (int e = 0; e < 16; ++e) rmx[e] = -1e30f;
  float cmx[2];
  cmx[0] = -1e30f; cmx[1] = -1e30f;

  #pragma unroll
  for (int mt = 0; mt < 4; ++mt){
    #pragma unroll
    for (int nt = 0; nt < 2; ++nt){
      int col = wc * 32 + nt * 16 + ln;
      bool colv = (j0 + col) < hc;
      #pragma unroll
      for (int rr = 0; rr < 4; ++rr){
        int row = wr * 64 + mt * 16 + q * 4 + rr;
        float f = S2 * ((float)acc1[mt][nt][rr] + (float)accc[mt][nt][rr] * 0.00390625f);
        simb[(size_t)row * SLB + col] = __half_as_ushort(__float2half(f));
        rmx[mt * 4 + rr] = fmaxf(rmx[mt * 4 + rr], colv ? f : -1e30f);
        cmx[nt] = fmaxf(cmx[nt], (i0 + row) < pc ? f : -1e30f);
      }
    }
  }

  #pragma unroll
  for (int e = 0; e < 16; ++e){
    float v = rmx[e];
    v = fmaxf(v, __shfl_xor(v, 1));
    v = fmaxf(v, __shfl_xor(v, 2));
    v = fmaxf(v, __shfl_xor(v, 4));
    v = fmaxf(v, __shfl_xor(v, 8));
    if (ln == 0){
      int row = wr * 64 + (e >> 2) * 16 + q * 4 + (e & 3);
      if (i0 + row < pc)
        atomicMax(rowMaxU + b * 1024 + i0 + row, fkey(v));
    }
  }
  #pragma unroll
  for (int nt = 0; nt < 2; ++nt){
    float v = cmx[nt];
    v = fmaxf(v, __shfl_xor(v, 16));
    v = fmaxf(v, __shfl_xor(v, 32));
    if (q == 0){
      int col = wc * 32 + nt * 16 + ln;
      if (j0 + col < hc)
        atomicMax(colMaxU + b * 1024 + j0 + col, fkey(v));
    }
  }
}

// ---------------------------------------------------------------------------
// build_pT: PhypT[b][jc][ic] = exp(sim[ic][jc] - colMax[jc]) bf16 (transposed)
// + colSum atomics. Pad fringe zeroed by count guards.
// ---------------------------------------------------------------------------
__global__ __launch_bounds__(256) void build_pt_kernel(
    const unsigned short* __restrict__ simH,
    const unsigned* __restrict__ colMaxU,
    const int* __restrict__ pCnt, const int* __restrict__ hCnt,
    const int* __restrict__ pPad, const int* __restrict__ hPad,
    unsigned short* __restrict__ PhypT, float* __restrict__ colSum)
{
  __shared__ unsigned short tp[64][72];
  __shared__ float sCM[64];

  const int b  = blockIdx.z;
  const int i0 = blockIdx.y * 64;
  const int j0 = blockIdx.x * 64;
  const int t  = threadIdx.x;

  const int pc = pCnt[b], hc = hCnt[b];
  if (i0 >= pPad[b] || j0 >= hPad[b]) return;

  if (t < 64) sCM[t] = funkey(colMaxU[b * 1024 + j0 + t]);
  __syncthreads();

  const unsigned short* sb = simH + (size_t)b * SLA * SLB;
  #pragma unroll
  for (int it = 0; it < 4; ++it){
    int r = (t >> 4) + it * 16;        // ic local
    int c = (t & 15) * 4;              // jc local
    uint2 u = *(const uint2*)(sb + (size_t)(i0 + r) * SLB + j0 + c);
    float s0 = h2f((unsigned short)(u.x & 0xffff));
    float s1 = h2f((unsigned short)(u.x >> 16));
    float s2 = h2f((unsigned short)(u.y & 0xffff));
    float s3 = h2f((unsigned short)(u.y >> 16));
    bool vi = (i0 + r) < pc;
    tp[c + 0][r] = f2bf((vi && (j0 + c + 0) < hc) ? __expf(s0 - sCM[c+0]) : 0.f);
    tp[c + 1][r] = f2bf((vi && (j0 + c + 1) < hc) ? __expf(s1 - sCM[c+1]) : 0.f);
    tp[c + 2][r] = f2bf((vi && (j0 + c + 2) < hc) ? __expf(s2 - sCM[c+2]) : 0.f);
    tp[c + 3][r] = f2bf((vi && (j0 + c + 3) < hc) ? __expf(s3 - sCM[c+3]) : 0.f);
  }
  __syncthreads();
  const int w   = t >> 2;              // jc local
  const int seg = (t & 3) * 16;        // ic local
  const uint4* src = (const uint4*)&tp[w][seg];
  uint4 u0 = src[0], u1 = src[1];
  uint4* dst = (uint4*)(PhypT + ((size_t)b * 1024 + j0 + w) * 1024 + i0 + seg);
  dst[0] = u0;
  dst[1] = u1;

  const unsigned short* us0 = (const unsigned short*)&u0;
  const unsigned short* us1 = (const unsigned short*)&u1;
  float cs = 0.f;
  #pragma unroll
  for (int e = 0; e < 8; ++e) cs += bf2f(us0[e]);
  #pragma unroll
  for (int e = 0; e < 8; ++e) cs += bf2f(us1[e]);
  cs += __shfl_xor(cs, 1);
  cs += __shfl_xor(cs, 2);
  if ((t & 3) == 0 && (j0 + w) < hc)
    atomicAdd(colSum + b * 1024 + j0 + w, cs);
}

// ---------------------------------------------------------------------------
// av2: both value GEMMs in one launch. blockIdx.z = b + 16*side.
// side 0 (prem): A = exp(sim_f16 - rowMax) built in staging (fused build_p),
//                rowSum accumulated in-register; B = HypT via gl2lds.
// side 1 (hyp):  A = PhypT (materialized), B = PremT, both gl2lds;
//                scale = 1/colSum.
// Epilogue scatters compact rows to original rows via index list.
// ---------------------------------------------------------------------------
__global__ __launch_bounds__(256, 4) void av2_kernel(
    const unsigned short* __restrict__ simH,
    const unsigned short* __restrict__ PhypT,
    const unsigned short* __restrict__ HypT, const unsigned short* __restrict__ PremT,
    const unsigned* __restrict__ rowMaxU, const float* __restrict__ colSum,
    const int* __restrict__ pIdx, const int* __restrict__ hIdx,
    const int* __restrict__ pCnt, const int* __restrict__ hCnt,
    const int* __restrict__ pPad, const int* __restrict__ hPad,
    float* __restrict__ out)
{
  __shared__ unsigned short sA[128 * 64];
  __shared__ unsigned short sB[128 * 64];
  __shared__ float sRM[128];     // side0: row maxes
  __shared__ float sScale[128];  // 1/sum
  __shared__ int   sIdx[128];

  const int side = blockIdx.z >> 4;
  const int b    = blockIdx.z & 15;
  const int m0   = blockIdx.y * 128;
  const int n0   = blockIdx.x * 128;
  const int t    = threadIdx.x;

  const int cnt  = side ? hCnt[b] : pCnt[b];
  const int hc   = hCnt[b];
  const int mpad = side ? hPad[b] : pPad[b];
  const int kpad = side ? pPad[b] : hPad[b];
  if (m0 >= mpad) return;

  const int* idx = (side ? hIdx : pIdx) + b * 1024;
  float* o = out + (size_t)side * NB * SLA * HH + (size_t)b * 1024 * 512;

  if (t < 128){
    sIdx[t] = idx[m0 + t];
    if (side){
      sScale[t] = 1.f / colSum[b * 1024 + m0 + t];
    } else {
      sRM[t] = funkey(rowMaxU[b * 1024 + m0 + t]);
    }
  }

  // B staging pattern (gl2lds)
  const int wv = t >> 6;
  const int L  = t & 63;
  const int lr = L >> 3;
  const int sw = L & 7;
  const int gkc = (sw ^ lr) * 8;

  // side0 A staging pattern
  const int ar  = t >> 1;          // 0..127 m-row
  const int akh = (t & 1) * 32;    // k half (elements)

  // frag pattern
  const int lane = t & 63;
  const int wr = (t >> 7) & 1;
  const int wc = (t >> 6) & 1;
  const int q  = lane >> 4;
  const int ln = lane & 15;
  const int fsw = ln & 7;

  const unsigned short* simb  = simH  + (size_t)b * 1024 * 1024;
  const unsigned short* Ahyp  = PhypT + (size_t)b * 1024 * 1024;
  const unsigned short* Bt    = (side ? PremT : HypT) + (size_t)b * 512 * 1024;

  float rs = 0.f;

  f32x4 acc[4][4];
  #pragma unroll
  for (int mt = 0; mt < 4; ++mt)
    #pragma unroll
    for (int nt = 0; nt < 4; ++nt)
      acc[mt][nt] = (f32x4){0.f, 0.f, 0.f, 0.f};

  for (int k0 = 0; k0 < kpad; k0 += 64){
    __syncthreads();   // prior frag reads done (also covers sRM/sIdx first iter)
    if (side == 0){
      // B first (loads in flight during A exp work)
      #pragma unroll
      for (int s = 0; s < 4; ++s){
        int row = wv * 32 + s * 8 + lr;
        gl2lds16(Bt + (size_t)(n0 + row) * 1024 + k0 + gkc, &sB[row * 64 + sw * 8]);
      }
      // A: read sim fp16 row, exp, accumulate row sum, ds_write swizzled
      const unsigned short* sp = simb + (size_t)(m0 + ar) * 1024 + k0 + akh;
      float rm = sRM[ar];
      #pragma unroll
      for (int cc = 0; cc < 4; ++cc){
        uint4 u = *(const uint4*)(sp + cc * 8);
        unsigned uw[4] = {u.x, u.y, u.z, u.w};
        int kb = k0 + akh + cc * 8;
        unsigned short pb[8];
        #pragma unroll
        for (int d = 0; d < 4; ++d){
          float v0 = h2f((unsigned short)(uw[d] & 0xffff));
          float v1 = h2f((unsigned short)(uw[d] >> 16));
          float p0 = (kb + d * 2 + 0) < hc ? __expf(v0 - rm) : 0.f;
          float p1 = (kb + d * 2 + 1) < hc ? __expf(v1 - rm) : 0.f;
          rs += p0 + p1;
          pb[d * 2]     = f2bf(p0);
          pb[d * 2 + 1] = f2bf(p1);
        }
        uint4 w;
        w.x = (unsigned)pb[0] | ((unsigned)pb[1] << 16);
        w.y = (unsigned)pb[2] | ((unsigned)pb[3] << 16);
        w.z = (unsigned)pb[4] | ((unsigned)pb[5] << 16);
        w.w = (unsigned)pb[6] | ((unsigned)pb[7] << 16);
        int c   = (t & 1) * 4 + cc;
        int pos = c ^ (ar & 7);
        *(uint4*)&sA[ar * 64 + pos * 8] = w;
      }
    } else {
      #pragma unroll
      for (int s = 0; s < 4; ++s){
        int row = wv * 32 + s * 8 + lr;
        gl2lds16(Ahyp + (size_t)(m0 + row) * 1024 + k0 + gkc, &sA[row * 64 + sw * 8]);
        gl2lds16(Bt   + (size_t)(n0 + row) * 1024 + k0 + gkc, &sB[row * 64 + sw * 8]);
      }
    }
    __syncthreads();

    #pragma unroll
    for (int h = 0; h < 2; ++h){
      s16x8 af[4], bfr[4];
      #pragma unroll
      for (int mt = 0; mt < 4; ++mt){
        int r = wr * 64 + mt * 16 + ln;
        af[mt] = *(const s16x8*)&sA[r * 64 + (((h << 2) + q) ^ fsw) * 8];
      }
      #pragma unroll
      for (int nt = 0; nt < 4; ++nt){
        int r = wc * 64 + nt * 16 + ln;
        bfr[nt] = *(const s16x8*)&sB[r * 64 + (((h << 2) + q) ^ fsw) * 8];
      }
      #pragma unroll
      for (int mt = 0; mt < 4; ++mt)
        #pragma unroll
        for (int nt = 0; nt < 4; ++nt)
          acc[mt][nt] = __builtin_amdgcn_mfma_f32_16x16x32_bf16(af[mt], bfr[nt], acc[mt][nt], 0, 0, 0);
    }
  }

  if (side == 0){
    rs += __shfl_xor(rs, 1);          // combine the two k-halves of row ar
    __syncthreads();                  // sA dead; reuse barrier before sScale write
    if ((t & 1) == 0) sScale[ar] = 1.f / rs;
    __syncthreads();
  }

  #pragma unroll
  for (int mt = 0; mt < 4; ++mt)
    #pragma unroll
    for (int nt = 0; nt < 4; ++nt){
      int col = n0 + wc * 64 + nt * 16 + ln;
      #pragma unroll
      for (int rr = 0; rr < 4; ++rr){
        int rowL = wr * 64 + mt * 16 + q * 4 + rr;
        if (m0 + rowL < cnt)
          o[(size_t)sIdx[rowL] * 512 + col] = acc[mt][nt][rr] * sScale[rowL];
      }
    }
}

// ---------------------------------------------------------------------------
extern "C" void kernel_launch(void* const* d_in, const int* in_sizes, int n_in,
                              void* d_out, int out_size, void* d_ws, size_t ws_size,
                              hipStream_t stream)
{
  const float* prem  = (const float*)d_in[0];
  const float* pmask = (const float*)d_in[1];
  const float* hyp   = (const float*)d_in[2];
  const float* hmask = (const float*)d_in[3];
  float* out = (float*)d_out;

  char* ws = (char*)d_ws;
  unsigned short* simH = (unsigned short*)(ws);                // fp16, 32 MB used
  unsigned* rowMaxU = (unsigned*)(ws + 67108864);
  unsigned* colMaxU = (unsigned*)(ws + 67108864 + 2 * 65536);
  float*    colSum  = (float*)(ws + 67108864 + 3 * 65536);
  int* pIdx = (int*)(ws + 67108864 + 4 * 65536);
  int* hIdx = (int*)(ws + 67108864 + 5 * 65536);
  int* pCnt = (int*)(ws + 67108864 + 6 * 65536);
  int* hCnt = (int*)(ws + 67108864 + 6 * 65536 + 256);
  int* pPad = (int*)(ws + 67108864 + 6 * 65536 + 512);
  int* hPad = (int*)(ws + 67108864 + 6 * 65536 + 768);
  const size_t base2 = 67108864 + 4 * 65536 + 1048576;   // 68419584 (layout-stable)
  char* premD1 = (char*)(ws + base2);
  char* premD0 = (char*)(ws + base2 + 8388608);
  char* hypD1  = (char*)(ws + base2 + 16777216);
  char* hypD0  = (char*)(ws + base2 + 25165824);
  unsigned short* PremT = (unsigned short*)(ws + base2 + 33554432);
  unsigned short* HypT  = (unsigned short*)(ws + base2 + 50331648);
  // PhypT aliases the digit planes (dead after sim_v5)
  unsigned short* PhypT = (unsigned short*)(ws + base2);
  const size_t need = base2 + 100663296;         // 169,082,880 (same as R1-R6)
  if (ws_size < need) return;

  scan_kernel<<<dim3(16, 2), 256, 0, stream>>>(pmask, hmask, pIdx, hIdx,
                                               pCnt, hCnt, pPad, hPad,
                                               rowMaxU, colMaxU, colSum);
  zero_out_kernel<<<dim3(8192), 256, 0, stream>>>(pmask, hmask, out);
  cvt_gather_kernel<<<dim3(8, 16, 32), 256, 0, stream>>>(
      prem, hyp, pIdx, hIdx, pCnt, hCnt, pPad, hPad,
      premD1, premD0, hypD1, hypD0, PremT, HypT);
  sim_gemm_v5_kernel<<<dim3(16, 8, NB), 256, 0, stream>>>(
      premD1, premD0, hypD1, hypD0, pCnt, hCnt, pPad, hPad,
      simH, rowMaxU, colMaxU);
  build_pt_kernel<<<dim3(16, 16, NB), 256, 0, stream>>>(
      simH, colMaxU, pCnt, hCnt, pPad, hPad, PhypT, colSum);
  av2_kernel<<<dim3(4, 8, 32), 256, 0, stream>>>(
      simH, PhypT, HypT, PremT, rowMaxU, colSum,
      pIdx, hIdx, pCnt, hCnt, pPad, hPad, out);
}